// Round 17
// baseline (363.538 us; speedup 1.0000x reference)
//
#include <hip/hip_runtime.h>
#include <stdint.h>
#include <stddef.h>

#define B_ 2
#define S_ 2048
#define D_ 1024
#define H_ 16
#define HD_ 64
#define FF_ 4096

typedef unsigned short u16;
typedef __attribute__((ext_vector_type(8))) short bf16x8;
typedef __attribute__((ext_vector_type(4))) float f32x4;

__device__ __forceinline__ u16 f2bf(float f) {
  unsigned u = __float_as_uint(f);
  u += 0x7fffu + ((u >> 16) & 1u);
  return (u16)(u >> 16);
}

__device__ __forceinline__ float bf2f(u16 u) {
  return __uint_as_float(((unsigned)u) << 16);
}

__device__ __forceinline__ f32x4 mfma16(bf16x8 a, bf16x8 b, f32x4 c) {
  return __builtin_amdgcn_mfma_f32_16x16x32_bf16(a, b, c, 0, 0, 0);
}

__device__ __forceinline__ void gload16(const void* g, void* l) {
  __builtin_amdgcn_global_load_lds(
      (const __attribute__((address_space(1))) void*)g,
      (__attribute__((address_space(3))) void*)l, 16, 0, 0);
}

// XCD-aware block swizzle (bijective when gridDim.x % 8 == 0).
__device__ __forceinline__ void swizzle_mn(int& mt, int& nt) {
  int gm = gridDim.x;
  if ((gm & 7) == 0) {
    int bid = blockIdx.y * gm + blockIdx.x;
    int mper = gm >> 3;
    int xcd = bid & 7, idx = bid >> 3;
    mt = xcd * mper + (idx % mper);
    nt = idx / mper;
  } else {
    mt = blockIdx.x;
    nt = blockIdx.y;
  }
}

// ---------------- fused prep: x cvt + all weight transposes ----------------
// 64x64 transpose tiles (128B write segments). grid 7168.
__global__ __launch_bounds__(256) void prep_kernel(
    const float* __restrict__ x, u16* __restrict__ xb,
    const float* __restrict__ W1, u16* __restrict__ w1T,
    const float* __restrict__ W2, u16* __restrict__ w2T,
    const float* __restrict__ Wq, const float* __restrict__ Wk,
    const float* __restrict__ Wv, const float* __restrict__ Wo,
    u16* __restrict__ wTq, u16* __restrict__ wTk,
    u16* __restrict__ wTv, u16* __restrict__ wTo) {
  int bid = blockIdx.x;
  int tid = threadIdx.x;
  if (bid >= 3072) {  // cvt path (no barrier)
    int i = (bid - 3072) * 1024 + tid * 4;
    float4 v = *(const float4*)(x + i);
    ushort4 o = { f2bf(v.x), f2bf(v.y), f2bf(v.z), f2bf(v.w) };
    *(ushort4*)(xb + i) = o;
    return;
  }
  const float* W;
  u16* WT;
  int K, N, k0, n0;
  if (bid < 1024) {        // W1: K=1024 N=4096
    W = W1; WT = w1T; K = 1024; N = 4096;
    k0 = (bid & 15) * 64; n0 = (bid >> 4) * 64;
  } else if (bid < 2048) { // W2: K=4096 N=1024
    int t2 = bid - 1024;
    W = W2; WT = w2T; K = 4096; N = 1024;
    k0 = (t2 >> 4) * 64; n0 = (t2 & 15) * 64;
  } else {                 // 4 x DxD
    int t2 = bid - 2048;
    int z = t2 >> 8, r2 = t2 & 255;
    W = z == 0 ? Wq : (z == 1 ? Wk : (z == 2 ? Wv : Wo));
    WT = z == 0 ? wTq : (z == 1 ? wTk : (z == 2 ? wTv : wTo));
    K = 1024; N = 1024;
    k0 = (r2 & 15) * 64; n0 = (r2 >> 4) * 64;
  }
  __shared__ u16 t[64][68];
  int rr = tid >> 4;          // 0..15
  int cc = (tid & 15) * 4;    // 0..60
#pragma unroll
  for (int p = 0; p < 4; p++) {
    int row = rr + p * 16;
    float4 v = *(const float4*)(W + (size_t)(k0 + row) * N + n0 + cc);
    t[row][cc + 0] = f2bf(v.x); t[row][cc + 1] = f2bf(v.y);
    t[row][cc + 2] = f2bf(v.z); t[row][cc + 3] = f2bf(v.w);
  }
  __syncthreads();
  int s = tid & 15;
#pragma unroll
  for (int p = 0; p < 4; p++) {
    int r = rr + p * 16;      // n-row within tile
    ushort4 o = { t[s * 4 + 0][r], t[s * 4 + 1][r],
                  t[s * 4 + 2][r], t[s * 4 + 3][r] };
    *(ushort4*)(WT + (size_t)(n0 + r) * K + k0 + s * 4) = o;
  }
}

// ======== 128^2 2-phase GEMM macros ========================================
#define GEMM_STAGE(BUF, KK)                      \
  do {                                           \
    gload16(ga0 + (KK), &As[BUF][c0 * 8]);       \
    gload16(ga1 + (KK), &As[BUF][c1 * 8]);       \
    gload16(gb0 + (KK), &Bs[BUF][c0 * 8]);       \
    gload16(gb1 + (KK), &Bs[BUF][c1 * 8]);       \
  } while (0)

#define GEMM_COMPUTE(BUF)                                                   \
  do {                                                                      \
    bf16x8 af[4], bfr[4];                                                   \
    _Pragma("unroll") for (int i = 0; i < 4; i++)                           \
        af[i] = *(const bf16x8*)&As[BUF][(wm + i * 16 + l16) * 32 + quad * 8]; \
    _Pragma("unroll") for (int j = 0; j < 4; j++)                           \
        bfr[j] = *(const bf16x8*)&Bs[BUF][(wn + j * 16 + l16) * 32 + quad * 8]; \
    _Pragma("unroll") for (int i = 0; i < 4; i++)                           \
        _Pragma("unroll") for (int j = 0; j < 4; j++)                       \
            acc[i][j] = mfma16(af[i], bfr[j], acc[i][j]);                   \
  } while (0)

// ======== 256^2 counted-vmcnt template (ffn1) ==============================
#define G2_STAGE(BUF, KK)                        \
  do {                                           \
    gload16(gA0 + (KK), &As[BUF][c0 * 8]);       \
    gload16(gA1 + (KK), &As[BUF][c1 * 8]);       \
    gload16(gB0 + (KK), &Bs[BUF][c0 * 8]);       \
    gload16(gB1 + (KK), &Bs[BUF][c1 * 8]);       \
  } while (0)

#define G2_COMPUTE(BUF)                                                        \
  do {                                                                         \
    bf16x8 bfr[4];                                                             \
    _Pragma("unroll") for (int j = 0; j < 4; j++)                              \
        bfr[j] = *(const bf16x8*)&Bs[BUF][(wn + j * 16 + l16) * 32 + quad * 8]; \
    _Pragma("unroll") for (int i = 0; i < 8; i++) {                            \
      bf16x8 af = *(const bf16x8*)&As[BUF][(wm + i * 16 + l16) * 32 + quad * 8]; \
      _Pragma("unroll") for (int j = 0; j < 4; j++)                            \
          acc[i][j] = mfma16(af, bfr[j], acc[i][j]);                           \
    }                                                                          \
  } while (0)

#define G2_STEP(BUF, NXT, KNEXT)                        \
  do {                                                  \
    G2_STAGE(NXT, KNEXT);                               \
    asm volatile("s_waitcnt vmcnt(4)" ::: "memory");    \
    __builtin_amdgcn_s_barrier();                       \
    asm volatile("" ::: "memory");                      \
    G2_COMPUTE(BUF);                                    \
    asm volatile("" ::: "memory");                      \
    __builtin_amdgcn_s_barrier();                       \
  } while (0)

// ---------------- GEMM 256x256 counted-vmcnt, out bf16+relu [ffn1] ---------
__global__ __launch_bounds__(512, 2) void gemm256_relu(
    const u16* __restrict__ A, const u16* __restrict__ BT,
    const float* __restrict__ bias, u16* __restrict__ outp,
    int M, int N, int K) {
  __shared__ __align__(16) u16 As[2][256 * 32];
  __shared__ __align__(16) u16 Bs[2][256 * 32];
  int tid = threadIdx.x;
  int lane = tid & 63;
  int wave = tid >> 6;            // 0..7
  int quad = lane >> 4;
  int l16 = lane & 15;
  int mt, nt;
  swizzle_mn(mt, nt);
  int m0 = mt * 256;
  int n0 = nt * 256;
  int wm = (wave >> 2) * 128;     // 2 M-groups
  int wn = (wave & 3) * 64;       // 4 N-groups

  f32x4 zero = {0.f, 0.f, 0.f, 0.f};
  f32x4 acc[8][4];
#pragma unroll
  for (int i = 0; i < 8; i++)
#pragma unroll
    for (int j = 0; j < 4; j++) acc[i][j] = zero;

  int c0 = tid, c1 = tid + 512;   // chunk: row = c>>2, kcol = (c&3)*8
  const u16* gA0 = A + (size_t)(m0 + (c0 >> 2)) * K + (c0 & 3) * 8;
  const u16* gA1 = A + (size_t)(m0 + (c1 >> 2)) * K + (c1 & 3) * 8;
  const u16* gB0 = BT + (size_t)(n0 + (c0 >> 2)) * K + (c0 & 3) * 8;
  const u16* gB1 = BT + (size_t)(n0 + (c1 >> 2)) * K + (c1 & 3) * 8;

  G2_STAGE(0, 0);
  for (int k0 = 0; k0 < K; k0 += 64) {
    G2_STEP(0, 1, (k0 + 32 < K) ? k0 + 32 : 0);
    G2_STEP(1, 0, (k0 + 64 < K) ? k0 + 64 : 0);
  }

#pragma unroll
  for (int j = 0; j < 4; j++) {
    int gcol = n0 + wn + j * 16 + l16;
    float bv = bias[gcol];
#pragma unroll
    for (int i = 0; i < 8; i++) {
#pragma unroll
      for (int r = 0; r < 4; r++) {
        int grow = m0 + wm + i * 16 + quad * 4 + r;
        float val = acc[i][j][r] + bv;
        outp[(size_t)grow * N + gcol] = f2bf(val > 0.f ? val : 0.f);
      }
    }
  }
}

// ---------------- GEMM 128x128 BK=32 2-phase split-K, bf16 partials --------
__global__ __launch_bounds__(256, 4) void gemm_bt_sk4(
    const u16* __restrict__ A, const u16* __restrict__ BT,
    const float* __restrict__ bias,
    u16* __restrict__ o0, u16* __restrict__ o1,
    u16* __restrict__ o2, u16* __restrict__ o3,
    int M, int N, int K, int Kc) {
  __shared__ __align__(16) u16 As[2][128 * 32];
  __shared__ __align__(16) u16 Bs[2][128 * 32];
  int tid = threadIdx.x;
  int lane = tid & 63;
  int wave = tid >> 6;
  int quad = lane >> 4;
  int l16 = lane & 15;
  int mt, nt;
  swizzle_mn(mt, nt);
  int m0 = mt * 128;
  int n0 = nt * 128;
  int z = blockIdx.z;
  int kb = z * Kc;
  int wm = (wave >> 1) * 64;
  int wn = (wave & 1) * 64;

  f32x4 zero = {0.f, 0.f, 0.f, 0.f};
  f32x4 acc[4][4];
#pragma unroll
  for (int i = 0; i < 4; i++)
#pragma unroll
    for (int j = 0; j < 4; j++) acc[i][j] = zero;

  int c0 = tid, c1 = tid + 256;
  const u16* ga0 = A + (size_t)(m0 + (c0 >> 2)) * K + (c0 & 3) * 8 + kb;
  const u16* ga1 = A + (size_t)(m0 + (c1 >> 2)) * K + (c1 & 3) * 8 + kb;
  const u16* gb0 = BT + (size_t)(n0 + (c0 >> 2)) * K + (c0 & 3) * 8 + kb;
  const u16* gb1 = BT + (size_t)(n0 + (c1 >> 2)) * K + (c1 & 3) * 8 + kb;

  GEMM_STAGE(0, 0);
  __syncthreads();
  for (int k0 = 0; k0 < Kc; k0 += 64) {
    if (k0 + 32 < Kc) GEMM_STAGE(1, k0 + 32);
    GEMM_COMPUTE(0);
    __syncthreads();
    if (k0 + 64 < Kc) GEMM_STAGE(0, k0 + 64);
    GEMM_COMPUTE(1);
    __syncthreads();
  }

  u16* outz = z == 0 ? o0 : (z == 1 ? o1 : (z == 2 ? o2 : o3));
  float biasmul = (z == 0) ? 1.f : 0.f;
#pragma unroll
  for (int j = 0; j < 4; j++) {
    int gcol = n0 + wn + j * 16 + l16;
    float bv = bias[gcol] * biasmul;
#pragma unroll
    for (int i = 0; i < 4; i++) {
#pragma unroll
      for (int r = 0; r < 4; r++) {
        int grow = m0 + wm + i * 16 + quad * 4 + r;
        outz[(size_t)grow * N + gcol] = f2bf(acc[i][j][r] + bv);
      }
    }
  }
}

// ---------------- fused QKV GEMM BK=32 2-phase -----------------------------
__global__ __launch_bounds__(256, 4) void gemm_qkv(
    const u16* __restrict__ A, const u16* __restrict__ BT,
    const float* __restrict__ bq, const float* __restrict__ bk,
    const float* __restrict__ bvp,
    u16* __restrict__ qb, u16* __restrict__ kb, u16* __restrict__ vb) {
  const int K = 1024;
  __shared__ __align__(16) u16 As[2][128 * 32];
  __shared__ __align__(16) u16 Bs[2][128 * 32];
  int tid = threadIdx.x;
  int lane = tid & 63;
  int wave = tid >> 6;
  int quad = lane >> 4;
  int l16 = lane & 15;
  int mt, nt;
  swizzle_mn(mt, nt);
  int m0 = mt * 128;
  int n0 = nt * 128;
  int wm = (wave >> 1) * 64;
  int wn = (wave & 1) * 64;

  f32x4 zero = {0.f, 0.f, 0.f, 0.f};
  f32x4 acc[4][4];
#pragma unroll
  for (int i = 0; i < 4; i++)
#pragma unroll
    for (int j = 0; j < 4; j++) acc[i][j] = zero;

  int c0 = tid, c1 = tid + 256;
  const u16* ga0 = A + (size_t)(m0 + (c0 >> 2)) * K + (c0 & 3) * 8;
  const u16* ga1 = A + (size_t)(m0 + (c1 >> 2)) * K + (c1 & 3) * 8;
  const u16* gb0 = BT + (size_t)(n0 + (c0 >> 2)) * K + (c0 & 3) * 8;
  const u16* gb1 = BT + (size_t)(n0 + (c1 >> 2)) * K + (c1 & 3) * 8;

  GEMM_STAGE(0, 0);
  __syncthreads();
  for (int k0 = 0; k0 < K; k0 += 64) {
    if (k0 + 32 < K) GEMM_STAGE(1, k0 + 32);
    GEMM_COMPUTE(0);
    __syncthreads();
    if (k0 + 64 < K) GEMM_STAGE(0, k0 + 64);
    GEMM_COMPUTE(1);
    __syncthreads();
  }

  int region = n0 >> 10;
  const float* bias = region == 0 ? bq : (region == 1 ? bk : bvp);
  u16* outp = region == 0 ? qb : (region == 1 ? kb : vb);
  float scale = region == 0 ? 0.125f * 1.4426950408889634f : 1.f;

#pragma unroll
  for (int j = 0; j < 4; j++) {
    int gcol = (n0 & 1023) + wn + j * 16 + l16;
    float bv = bias[gcol];
    int h = gcol >> 6, hd = gcol & 63;
#pragma unroll
    for (int i = 0; i < 4; i++) {
#pragma unroll
      for (int r = 0; r < 4; r++) {
        int grow = m0 + wm + i * 16 + quad * 4 + r;
        float val = (acc[i][j][r] + bv) * scale;
        int b = grow >> 11, s = grow & 2047;
        if (region < 2) {
          outp[(((size_t)(b * H_ + h)) * S_ + s) * HD_ + hd] = f2bf(val);
        } else {
          outp[(((size_t)(b * H_ + h)) * HD_ + hd) * S_ + s] = f2bf(val);
        }
      }
    }
  }
}

// ---------------- flash attention: MQ=32/wave, double-buffered K/V ---------
// (measured plateau 72.5 us; linear decode, 2 blocks/CU = mapped optimum)
__global__ __launch_bounds__(256, 2) void attn_kernel(
    const u16* __restrict__ q, const u16* __restrict__ k,
    const u16* __restrict__ vt, const int* __restrict__ mask,
    u16* __restrict__ ao, int qbase) {
  __shared__ __align__(16) u16 Ks[2][64 * 72];
  __shared__ __align__(16) u16 Vs[2][64 * 72];
  __shared__ __align__(16) u16 Ps[4][32 * 72];
  int tid = threadIdx.x;
  int lane = tid & 63;
  int wave = tid >> 6;
  int quad = lane >> 4;
  int l16 = lane & 15;
  int bh = blockIdx.y;
  int b = bh >> 4;
  int h = bh & 15;
  int qrow0 = (qbase + blockIdx.x) * 128 + wave * 32;

  const u16* qh = q + (size_t)bh * S_ * HD_;
  const u16* kh = k + (size_t)bh * S_ * HD_;
  const u16* vh = vt + (size_t)bh * HD_ * S_;

  bf16x8 qfA0 = *(const bf16x8*)(qh + (size_t)(qrow0 + l16) * HD_ + quad * 8);
  bf16x8 qfA1 = *(const bf16x8*)(qh + (size_t)(qrow0 + l16) * HD_ + 32 + quad * 8);
  bf16x8 qfB0 = *(const bf16x8*)(qh + (size_t)(qrow0 + 16 + l16) * HD_ + quad * 8);
  bf16x8 qfB1 = *(const bf16x8*)(qh + (size_t)(qrow0 + 16 + l16) * HD_ + 32 + quad * 8);

  int sr = tid >> 3, sc = tid & 7;
  const u16* kg0 = kh + sr * HD_ + sc * 8;
  const u16* kg1 = kh + (sr + 32) * HD_ + sc * 8;
  const u16* vg0 = vh + (size_t)sr * S_ + sc * 8;
  const u16* vg1 = vh + (size_t)(sr + 32) * S_ + sc * 8;
  int kr0 = (sr & 1) * 16 + (sr >> 1);
  int ko0 = kr0 * 72 + sc * 8;
  int ko1 = (32 + kr0) * 72 + sc * 8;
  int vo0 = sr * 72 + sc * 8;
  int vo1 = (sr + 32) * 72 + sc * 8;
  const int* mrow = mask + b * S_ + 2 * l16;

  float l_pA[4] = {0.f, 0.f, 0.f, 0.f};
  float l_pB[4] = {0.f, 0.f, 0.f, 0.f};
  f32x4 zero = {0.f, 0.f, 0.f, 0.f};
  f32x4 o_accA[4], o_accB[4];
#pragma unroll
  for (int c = 0; c < 4; c++) { o_accA[c] = zero; o_accB[c] = zero; }

  u16* pw = &Ps[wave][0];

  bf16x8 kv0 = *(const bf16x8*)(kg0);
  bf16x8 kv1 = *(const bf16x8*)(kg1);
  bf16x8 vv0 = *(const bf16x8*)(vg0);
  bf16x8 vv1 = *(const bf16x8*)(vg1);
  *(bf16x8*)&Ks[0][ko0] = kv0;
  *(bf16x8*)&Ks[0][ko1] = kv1;
  *(bf16x8*)&Vs[0][vo0] = vv0;
  *(bf16x8*)&Vs[0][vo1] = vv1;
  kv0 = *(const bf16x8*)(kg0 + (size_t)64 * HD_);
  kv1 = *(const bf16x8*)(kg1 + (size_t)64 * HD_);
  vv0 = *(const bf16x8*)(vg0 + 64);
  vv1 = *(const bf16x8*)(vg1 + 64);

  int cur = 0;
  for (int kt = 0; kt < S_; kt += 64) {
    int2 mk0 = *(const int2*)(mrow + kt);
    int2 mk1 = *(const int2*)(mrow + kt + 32);

    __syncthreads();
    if (kt + 64 < S_) {
      int alt = cur ^ 1;
      *(bf16x8*)&Ks[alt][ko0] = kv0;
      *(bf16x8*)&Ks[alt][ko1] = kv1;
      *(bf16x8*)&Vs[alt][vo0] = vv0;
      *(bf16x8*)&Vs[alt][vo1] = vv1;
      int nk = (kt + 128) & (S_ - 1);
      kv0 = *(const bf16x8*)(kg0 + (size_t)nk * HD_);
      kv1 = *(const bf16x8*)(kg1 + (size_t)nk * HD_);
      vv0 = *(const bf16x8*)(vg0 + nk);
      vv1 = *(const bf16x8*)(vg1 + nk);
    }

    const u16* ksb = &Ks[cur][0];
    const u16* vsb = &Vs[cur][0];
#pragma unroll
    for (int g = 0; g < 2; g++) {
      int2 mk = g == 0 ? mk0 : mk1;
      int rowe = (g * 32 + l16) * 72;
      int rowo = (g * 32 + 16 + l16) * 72;
      bf16x8 e0 = *(const bf16x8*)&ksb[rowe + quad * 8];
      bf16x8 e1 = *(const bf16x8*)&ksb[rowe + 32 + quad * 8];
      bf16x8 o0 = *(const bf16x8*)&ksb[rowo + quad * 8];
      bf16x8 o1 = *(const bf16x8*)&ksb[rowo + 32 + quad * 8];
      f32x4 seA = mfma16(qfA1, e1, mfma16(qfA0, e0, zero));
      f32x4 soA = mfma16(qfA1, o1, mfma16(qfA0, o0, zero));
      f32x4 seB = mfma16(qfB1, e1, mfma16(qfB0, e0, zero));
      f32x4 soB = mfma16(qfB1, o1, mfma16(qfB0, o0, zero));
#pragma unroll
      for (int r = 0; r < 4; r++) {
        float pA0 = mk.x ? exp2f(seA[r]) : 0.f;
        float pA1 = mk.y ? exp2f(soA[r]) : 0.f;
        float pB0 = mk.x ? exp2f(seB[r]) : 0.f;
        float pB1 = mk.y ? exp2f(soB[r]) : 0.f;
        l_pA[r] += pA0 + pA1;
        l_pB[r] += pB0 + pB1;
        unsigned pkA = __builtin_amdgcn_perm(__float_as_uint(pA1),
                                             __float_as_uint(pA0), 0x07060302u);
        unsigned pkB = __builtin_amdgcn_perm(__float_as_uint(pB1),
                                             __float_as_uint(pB0), 0x07060302u);
        *(unsigned*)&pw[(quad * 4 + r) * 72 + g * 32 + 2 * l16] = pkA;
        *(unsigned*)&pw[(16 + quad * 4 + r) * 72 + g * 32 + 2 * l16] = pkB;
      }
    }
    bf16x8 pfA0 = *(const bf16x8*)&pw[l16 * 72 + quad * 8];
    bf16x8 pfA1 = *(const bf16x8*)&pw[l16 * 72 + 32 + quad * 8];
    bf16x8 pfB0 = *(const bf16x8*)&pw[(16 + l16) * 72 + quad * 8];
    bf16x8 pfB1 = *(const bf16x8*)&pw[(16 + l16) * 72 + 32 + quad * 8];
#pragma unroll
    for (int c = 0; c < 4; c++) {
      bf16x8 vf0 = *(const bf16x8*)&vsb[(c * 16 + l16) * 72 + quad * 8];
      bf16x8 vf1 = *(const bf16x8*)&vsb[(c * 16 + l16) * 72 + 32 + quad * 8];
      o_accA[c] = mfma16(pfA1, vf1, mfma16(pfA0, vf0, o_accA[c]));
      o_accB[c] = mfma16(pfB1, vf1, mfma16(pfB0, vf0, o_accB[c]));
    }
    cur ^= 1;
  }

#pragma unroll
  for (int r = 0; r < 4; r++) {
    float sA = l_pA[r], sB = l_pB[r];
#pragma unroll
    for (int off = 1; off < 16; off <<= 1) {
      sA += __shfl_xor(sA, off);
      sB += __shfl_xor(sB, off);
    }
    float invA = 1.f / sA, invB = 1.f / sB;
    int srowA = qrow0 + quad * 4 + r;
    int srowB = qrow0 + 16 + quad * 4 + r;
#pragma unroll
    for (int c = 0; c < 4; c++) {
      ao[((size_t)(b * S_ + srowA)) * D_ + h * HD_ + c * 16 + l16] =
          f2bf(o_accA[c][r] * invA);
      ao[((size_t)(b * S_ + srowB)) * D_ + h * HD_ + c * 16 + l16] =
          f2bf(o_accB[c][r] * invB);
    }
  }
}

// ---------------- residual (f32 base + 2 bf16 partials) + layernorm --------
__global__ __launch_bounds__(256) void ln_kernel(
    const float* __restrict__ xa, const u16* __restrict__ add0,
    const u16* __restrict__ add1,
    const float* __restrict__ g, const float* __restrict__ be,
    u16* __restrict__ outb) {
  int row = blockIdx.x;
  int tid = threadIdx.x;
  int lane = tid & 63;
  int wv = tid >> 6;
  size_t off0 = (size_t)row * D_ + tid * 4;
  const float4 a = *(const float4*)(xa + off0);
  const ushort4 c = *(const ushort4*)(add0 + off0);
  const ushort4 d = *(const ushort4*)(add1 + off0);
  float v0 = a.x + bf2f(c.x) + bf2f(d.x);
  float v1 = a.y + bf2f(c.y) + bf2f(d.y);
  float v2 = a.z + bf2f(c.z) + bf2f(d.z);
  float v3 = a.w + bf2f(c.w) + bf2f(d.w);
  float s = v0 + v1 + v2 + v3;
  float sq = v0 * v0 + v1 * v1 + v2 * v2 + v3 * v3;
#pragma unroll
  for (int off = 1; off < 64; off <<= 1) {
    s += __shfl_xor(s, off);
    sq += __shfl_xor(sq, off);
  }
  __shared__ float red[8];
  if (lane == 0) { red[wv] = s; red[4 + wv] = sq; }
  __syncthreads();
  s = red[0] + red[1] + red[2] + red[3];
  sq = red[4] + red[5] + red[6] + red[7];
  float mean = s * (1.f / D_);
  float var = sq * (1.f / D_) - mean * mean;
  float rstd = rsqrtf(var + 1e-5f);
  const float4 gv = *(const float4*)(g + tid * 4);
  const float4 bv = *(const float4*)(be + tid * 4);
  float y0 = (v0 - mean) * rstd * gv.x + bv.x;
  float y1 = (v1 - mean) * rstd * gv.y + bv.y;
  float y2 = (v2 - mean) * rstd * gv.z + bv.z;
  float y3 = (v3 - mean) * rstd * gv.w + bv.w;
  ushort4 ob = {f2bf(y0), f2bf(y1), f2bf(y2), f2bf(y3)};
  *(ushort4*)(outb + off0) = ob;
}

// ---------------- residual (bf16 base + 4 bf16 partials) + layernorm -------
__global__ __launch_bounds__(256) void ln4_kernel(
    const u16* __restrict__ xa,
    const u16* __restrict__ a0, const u16* __restrict__ a1,
    const u16* __restrict__ a2, const u16* __restrict__ a3,
    const float* __restrict__ g, const float* __restrict__ be,
    float* __restrict__ outf) {
  int row = blockIdx.x;
  int tid = threadIdx.x;
  int lane = tid & 63;
  int wv = tid >> 6;
  size_t off0 = (size_t)row * D_ + tid * 4;
  const ushort4 a = *(const ushort4*)(xa + off0);
  const ushort4 c0 = *(const ushort4*)(a0 + off0);
  const ushort4 c1 = *(const ushort4*)(a1 + off0);
  const ushort4 c2 = *(const ushort4*)(a2 + off0);
  const ushort4 c3 = *(const ushort4*)(a3 + off0);
  float v0 = bf2f(a.x) + (bf2f(c0.x) + bf2f(c1.x)) + (bf2f(c2.x) + bf2f(c3.x));
  float v1 = bf2f(a.y) + (bf2f(c0.y) + bf2f(c1.y)) + (bf2f(c2.y) + bf2f(c3.y));
  float v2 = bf2f(a.z) + (bf2f(c0.z) + bf2f(c1.z)) + (bf2f(c2.z) + bf2f(c3.z));
  float v3 = bf2f(a.w) + (bf2f(c0.w) + bf2f(c1.w)) + (bf2f(c2.w) + bf2f(c3.w));
  float s = v0 + v1 + v2 + v3;
  float sq = v0 * v0 + v1 * v1 + v2 * v2 + v3 * v3;
#pragma unroll
  for (int off = 1; off < 64; off <<= 1) {
    s += __shfl_xor(s, off);
    sq += __shfl_xor(sq, off);
  }
  __shared__ float red[8];
  if (lane == 0) { red[wv] = s; red[4 + wv] = sq; }
  __syncthreads();
  s = red[0] + red[1] + red[2] + red[3];
  sq = red[4] + red[5] + red[6] + red[7];
  float mean = s * (1.f / D_);
  float var = sq * (1.f / D_) - mean * mean;
  float rstd = rsqrtf(var + 1e-5f);
  const float4 gv = *(const float4*)(g + tid * 4);
  const float4 bv = *(const float4*)(be + tid * 4);
  float y0 = (v0 - mean) * rstd * gv.x + bv.x;
  float y1 = (v1 - mean) * rstd * gv.y + bv.y;
  float y2 = (v2 - mean) * rstd * gv.z + bv.z;
  float y3 = (v3 - mean) * rstd * gv.w + bv.w;
  float4 o = {y0, y1, y2, y3};
  *(float4*)(outf + off0) = o;
}

extern "C" void kernel_launch(void* const* d_in, const int* in_sizes, int n_in,
                              void* d_out, int out_size, void* d_ws, size_t ws_size,
                              hipStream_t stream) {
  const float* x = (const float*)d_in[0];
  const int* mask = (const int*)d_in[1];
  const float* Wq = (const float*)d_in[2];
  const float* bq = (const float*)d_in[3];
  const float* Wk = (const float*)d_in[4];
  const float* bk = (const float*)d_in[5];
  const float* Wv = (const float*)d_in[6];
  const float* bv = (const float*)d_in[7];
  const float* Wo = (const float*)d_in[8];
  const float* bo = (const float*)d_in[9];
  const float* W1 = (const float*)d_in[10];
  const float* b1 = (const float*)d_in[11];
  const float* W2 = (const float*)d_in[12];
  const float* b2 = (const float*)d_in[13];
  const float* g1 = (const float*)d_in[14];
  const float* be1 = (const float*)d_in[15];
  const float* g2 = (const float*)d_in[16];
  const float* be2 = (const float*)d_in[17];

  const size_t MB = 1ull << 20;
  char* ws = (char*)d_ws;
  u16* wTq = (u16*)(ws + 0 * MB);   // [wTq;wTk;wTv] contiguous = fused QKV BT
  u16* wTk = (u16*)(ws + 2 * MB);
  u16* wTv = (u16*)(ws + 4 * MB);
  u16* wTo = (u16*)(ws + 6 * MB);
  u16* w1T = (u16*)(ws + 8 * MB);   // FF x D
  u16* w2T = (u16*)(ws + 16 * MB);  // D x FF (live through ffn2)
  u16* xb  = (u16*)(ws + 24 * MB);  // bf16 x (qkv A operand)
  u16* qb  = (u16*)(ws + 32 * MB);
  u16* kb  = (u16*)(ws + 40 * MB);
  u16* vb  = (u16*)(ws + 48 * MB);
  u16* ao  = (u16*)(ws + 56 * MB);
  u16* p0  = (u16*)(ws + 64 * MB);   // proj partials (bf16, 8MB each)
  u16* p1  = (u16*)(ws + 80 * MB);
  u16* x1b = (u16*)(ws + 40 * MB);   // reuse kb (dead after attn); live to ln4
  u16* h1  = (u16*)(ws + 48 * MB);   // 48..80 (vb/ao dead after ffn1 input)
  u16* f0  = (u16*)(ws + 80 * MB);   // ffn2 partials bf16 (p1 dead after LN1)
  u16* f1  = (u16*)(ws + 96 * MB);
  u16* f2  = (u16*)(ws + 112 * MB);
  u16* f3  = (u16*)(ws + 0 * MB);    // weights 0..16 dead by ffn2 time

  // fused prep (x cvt + all 6 weight transposes, 64x64 tiles) — 1 launch
  prep_kernel<<<dim3(7168), dim3(256), 0, stream>>>(
      x, xb, W1, w1T, W2, w2T, Wq, Wk, Wv, Wo, wTq, wTk, wTv, wTo);

  gemm_qkv<<<dim3(32, 24), dim3(256), 0, stream>>>(xb, wTq, bq, bk, bv, qb, kb, vb);

  // attn: MQ=32/wave, 512 blocks (2/CU)
  attn_kernel<<<dim3(16, B_ * H_), dim3(256), 0, stream>>>(qb, kb, vb, mask, ao, 0);

  // proj: split-K x2 (512 blocks), bf16 partials p0,p1
  gemm_bt_sk4<<<dim3(32, 8, 2), dim3(256), 0, stream>>>(
      ao, wTo, bo, p0, p1, p0, p0, 4096, 1024, 1024, 512);

  // LN1: f32 base x + bf16 partials -> bf16 x1b
  ln_kernel<<<dim3(4096), dim3(256), 0, stream>>>(
      x, p0, p1, g1, be1, x1b);

  // ffn1: 256^2 counted-vmcnt template, 256 blocks (1/CU)
  gemm256_relu<<<dim3(16, 16), dim3(512), 0, stream>>>(
      x1b, w1T, b1, h1, 4096, 4096, 1024);

  // ffn2: 128^2 2-phase split-K x4 (1024 blocks, 4/CU), bf16 partials f0..f3
  gemm_bt_sk4<<<dim3(32, 8, 4), dim3(256), 0, stream>>>(
      h1, w2T, b2, f0, f1, f2, f3, 4096, 1024, 4096, 1024);

  ln4_kernel<<<dim3(4096), dim3(256), 0, stream>>>(
      x1b, f0, f1, f2, f3, g2, be2, (float*)d_out);
}

// Round 18
// 357.052 us; speedup vs baseline: 1.0182x; 1.0182x over previous
//
#include <hip/hip_runtime.h>
#include <stdint.h>
#include <stddef.h>

#define B_ 2
#define S_ 2048
#define D_ 1024
#define H_ 16
#define HD_ 64
#define FF_ 4096

typedef unsigned short u16;
typedef __attribute__((ext_vector_type(8))) short bf16x8;
typedef __attribute__((ext_vector_type(4))) float f32x4;

__device__ __forceinline__ u16 f2bf(float f) {
  unsigned u = __float_as_uint(f);
  u += 0x7fffu + ((u >> 16) & 1u);
  return (u16)(u >> 16);
}

__device__ __forceinline__ float bf2f(u16 u) {
  return __uint_as_float(((unsigned)u) << 16);
}

__device__ __forceinline__ f32x4 mfma16(bf16x8 a, bf16x8 b, f32x4 c) {
  return __builtin_amdgcn_mfma_f32_16x16x32_bf16(a, b, c, 0, 0, 0);
}

__device__ __forceinline__ void gload16(const void* g, void* l) {
  __builtin_amdgcn_global_load_lds(
      (const __attribute__((address_space(1))) void*)g,
      (__attribute__((address_space(3))) void*)l, 16, 0, 0);
}

// XCD-aware block swizzle (bijective when gridDim.x % 8 == 0).
__device__ __forceinline__ void swizzle_mn(int& mt, int& nt) {
  int gm = gridDim.x;
  if ((gm & 7) == 0) {
    int bid = blockIdx.y * gm + blockIdx.x;
    int mper = gm >> 3;
    int xcd = bid & 7, idx = bid >> 3;
    mt = xcd * mper + (idx % mper);
    nt = idx / mper;
  } else {
    mt = blockIdx.x;
    nt = blockIdx.y;
  }
}

// ---------------- fused prep: x cvt + all weight transposes ----------------
// 64x64 transpose tiles (128B write segments). grid 7168.
__global__ __launch_bounds__(256) void prep_kernel(
    const float* __restrict__ x, u16* __restrict__ xb,
    const float* __restrict__ W1, u16* __restrict__ w1T,
    const float* __restrict__ W2, u16* __restrict__ w2T,
    const float* __restrict__ Wq, const float* __restrict__ Wk,
    const float* __restrict__ Wv, const float* __restrict__ Wo,
    u16* __restrict__ wTq, u16* __restrict__ wTk,
    u16* __restrict__ wTv, u16* __restrict__ wTo) {
  int bid = blockIdx.x;
  int tid = threadIdx.x;
  if (bid >= 3072) {  // cvt path (no barrier)
    int i = (bid - 3072) * 1024 + tid * 4;
    float4 v = *(const float4*)(x + i);
    ushort4 o = { f2bf(v.x), f2bf(v.y), f2bf(v.z), f2bf(v.w) };
    *(ushort4*)(xb + i) = o;
    return;
  }
  const float* W;
  u16* WT;
  int K, N, k0, n0;
  if (bid < 1024) {        // W1: K=1024 N=4096
    W = W1; WT = w1T; K = 1024; N = 4096;
    k0 = (bid & 15) * 64; n0 = (bid >> 4) * 64;
  } else if (bid < 2048) { // W2: K=4096 N=1024
    int t2 = bid - 1024;
    W = W2; WT = w2T; K = 4096; N = 1024;
    k0 = (t2 >> 4) * 64; n0 = (t2 & 15) * 64;
  } else {                 // 4 x DxD
    int t2 = bid - 2048;
    int z = t2 >> 8, r2 = t2 & 255;
    W = z == 0 ? Wq : (z == 1 ? Wk : (z == 2 ? Wv : Wo));
    WT = z == 0 ? wTq : (z == 1 ? wTk : (z == 2 ? wTv : wTo));
    K = 1024; N = 1024;
    k0 = (r2 & 15) * 64; n0 = (r2 >> 4) * 64;
  }
  __shared__ u16 t[64][68];
  int rr = tid >> 4;          // 0..15
  int cc = (tid & 15) * 4;    // 0..60
#pragma unroll
  for (int p = 0; p < 4; p++) {
    int row = rr + p * 16;
    float4 v = *(const float4*)(W + (size_t)(k0 + row) * N + n0 + cc);
    t[row][cc + 0] = f2bf(v.x); t[row][cc + 1] = f2bf(v.y);
    t[row][cc + 2] = f2bf(v.z); t[row][cc + 3] = f2bf(v.w);
  }
  __syncthreads();
  int s = tid & 15;
#pragma unroll
  for (int p = 0; p < 4; p++) {
    int r = rr + p * 16;      // n-row within tile
    ushort4 o = { t[s * 4 + 0][r], t[s * 4 + 1][r],
                  t[s * 4 + 2][r], t[s * 4 + 3][r] };
    *(ushort4*)(WT + (size_t)(n0 + r) * K + k0 + s * 4) = o;
  }
}

// ======== 128^2 2-phase GEMM macros ========================================
#define GEMM_STAGE(BUF, KK)                      \
  do {                                           \
    gload16(ga0 + (KK), &As[BUF][c0 * 8]);       \
    gload16(ga1 + (KK), &As[BUF][c1 * 8]);       \
    gload16(gb0 + (KK), &Bs[BUF][c0 * 8]);       \
    gload16(gb1 + (KK), &Bs[BUF][c1 * 8]);       \
  } while (0)

#define GEMM_COMPUTE(BUF)                                                   \
  do {                                                                      \
    bf16x8 af[4], bfr[4];                                                   \
    _Pragma("unroll") for (int i = 0; i < 4; i++)                           \
        af[i] = *(const bf16x8*)&As[BUF][(wm + i * 16 + l16) * 32 + quad * 8]; \
    _Pragma("unroll") for (int j = 0; j < 4; j++)                           \
        bfr[j] = *(const bf16x8*)&Bs[BUF][(wn + j * 16 + l16) * 32 + quad * 8]; \
    _Pragma("unroll") for (int i = 0; i < 4; i++)                           \
        _Pragma("unroll") for (int j = 0; j < 4; j++)                       \
            acc[i][j] = mfma16(af[i], bfr[j], acc[i][j]);                   \
  } while (0)

// ======== 256^2 counted-vmcnt template (ffn1) ==============================
#define G2_STAGE(BUF, KK)                        \
  do {                                           \
    gload16(gA0 + (KK), &As[BUF][c0 * 8]);       \
    gload16(gA1 + (KK), &As[BUF][c1 * 8]);       \
    gload16(gB0 + (KK), &Bs[BUF][c0 * 8]);       \
    gload16(gB1 + (KK), &Bs[BUF][c1 * 8]);       \
  } while (0)

#define G2_COMPUTE(BUF)                                                        \
  do {                                                                         \
    bf16x8 bfr[4];                                                             \
    _Pragma("unroll") for (int j = 0; j < 4; j++)                              \
        bfr[j] = *(const bf16x8*)&Bs[BUF][(wn + j * 16 + l16) * 32 + quad * 8]; \
    _Pragma("unroll") for (int i = 0; i < 8; i++) {                            \
      bf16x8 af = *(const bf16x8*)&As[BUF][(wm + i * 16 + l16) * 32 + quad * 8]; \
      _Pragma("unroll") for (int j = 0; j < 4; j++)                            \
          acc[i][j] = mfma16(af, bfr[j], acc[i][j]);                           \
    }                                                                          \
  } while (0)

#define G2_STEP(BUF, NXT, KNEXT)                        \
  do {                                                  \
    G2_STAGE(NXT, KNEXT);                               \
    asm volatile("s_waitcnt vmcnt(4)" ::: "memory");    \
    __builtin_amdgcn_s_barrier();                       \
    asm volatile("" ::: "memory");                      \
    G2_COMPUTE(BUF);                                    \
    asm volatile("" ::: "memory");                      \
    __builtin_amdgcn_s_barrier();                       \
  } while (0)

// ---------------- GEMM 256x256 counted-vmcnt, out bf16+relu [ffn1] ---------
__global__ __launch_bounds__(512, 2) void gemm256_relu(
    const u16* __restrict__ A, const u16* __restrict__ BT,
    const float* __restrict__ bias, u16* __restrict__ outp,
    int M, int N, int K) {
  __shared__ __align__(16) u16 As[2][256 * 32];
  __shared__ __align__(16) u16 Bs[2][256 * 32];
  int tid = threadIdx.x;
  int lane = tid & 63;
  int wave = tid >> 6;            // 0..7
  int quad = lane >> 4;
  int l16 = lane & 15;
  int mt, nt;
  swizzle_mn(mt, nt);
  int m0 = mt * 256;
  int n0 = nt * 256;
  int wm = (wave >> 2) * 128;     // 2 M-groups
  int wn = (wave & 3) * 64;       // 4 N-groups

  f32x4 zero = {0.f, 0.f, 0.f, 0.f};
  f32x4 acc[8][4];
#pragma unroll
  for (int i = 0; i < 8; i++)
#pragma unroll
    for (int j = 0; j < 4; j++) acc[i][j] = zero;

  int c0 = tid, c1 = tid + 512;   // chunk: row = c>>2, kcol = (c&3)*8
  const u16* gA0 = A + (size_t)(m0 + (c0 >> 2)) * K + (c0 & 3) * 8;
  const u16* gA1 = A + (size_t)(m0 + (c1 >> 2)) * K + (c1 & 3) * 8;
  const u16* gB0 = BT + (size_t)(n0 + (c0 >> 2)) * K + (c0 & 3) * 8;
  const u16* gB1 = BT + (size_t)(n0 + (c1 >> 2)) * K + (c1 & 3) * 8;

  G2_STAGE(0, 0);
  for (int k0 = 0; k0 < K; k0 += 64) {
    G2_STEP(0, 1, (k0 + 32 < K) ? k0 + 32 : 0);
    G2_STEP(1, 0, (k0 + 64 < K) ? k0 + 64 : 0);
  }

#pragma unroll
  for (int j = 0; j < 4; j++) {
    int gcol = n0 + wn + j * 16 + l16;
    float bv = bias[gcol];
#pragma unroll
    for (int i = 0; i < 8; i++) {
#pragma unroll
      for (int r = 0; r < 4; r++) {
        int grow = m0 + wm + i * 16 + quad * 4 + r;
        float val = acc[i][j][r] + bv;
        outp[(size_t)grow * N + gcol] = f2bf(val > 0.f ? val : 0.f);
      }
    }
  }
}

// ---------------- GEMM 128x128 BK=32 2-phase split-K, bf16 partials --------
__global__ __launch_bounds__(256, 4) void gemm_bt_sk4(
    const u16* __restrict__ A, const u16* __restrict__ BT,
    const float* __restrict__ bias,
    u16* __restrict__ o0, u16* __restrict__ o1,
    u16* __restrict__ o2, u16* __restrict__ o3,
    int M, int N, int K, int Kc) {
  __shared__ __align__(16) u16 As[2][128 * 32];
  __shared__ __align__(16) u16 Bs[2][128 * 32];
  int tid = threadIdx.x;
  int lane = tid & 63;
  int wave = tid >> 6;
  int quad = lane >> 4;
  int l16 = lane & 15;
  int mt, nt;
  swizzle_mn(mt, nt);
  int m0 = mt * 128;
  int n0 = nt * 128;
  int z = blockIdx.z;
  int kb = z * Kc;
  int wm = (wave >> 1) * 64;
  int wn = (wave & 1) * 64;

  f32x4 zero = {0.f, 0.f, 0.f, 0.f};
  f32x4 acc[4][4];
#pragma unroll
  for (int i = 0; i < 4; i++)
#pragma unroll
    for (int j = 0; j < 4; j++) acc[i][j] = zero;

  int c0 = tid, c1 = tid + 256;
  const u16* ga0 = A + (size_t)(m0 + (c0 >> 2)) * K + (c0 & 3) * 8 + kb;
  const u16* ga1 = A + (size_t)(m0 + (c1 >> 2)) * K + (c1 & 3) * 8 + kb;
  const u16* gb0 = BT + (size_t)(n0 + (c0 >> 2)) * K + (c0 & 3) * 8 + kb;
  const u16* gb1 = BT + (size_t)(n0 + (c1 >> 2)) * K + (c1 & 3) * 8 + kb;

  GEMM_STAGE(0, 0);
  __syncthreads();
  for (int k0 = 0; k0 < Kc; k0 += 64) {
    if (k0 + 32 < Kc) GEMM_STAGE(1, k0 + 32);
    GEMM_COMPUTE(0);
    __syncthreads();
    if (k0 + 64 < Kc) GEMM_STAGE(0, k0 + 64);
    GEMM_COMPUTE(1);
    __syncthreads();
  }

  u16* outz = z == 0 ? o0 : (z == 1 ? o1 : (z == 2 ? o2 : o3));
  float biasmul = (z == 0) ? 1.f : 0.f;
#pragma unroll
  for (int j = 0; j < 4; j++) {
    int gcol = n0 + wn + j * 16 + l16;
    float bv = bias[gcol] * biasmul;
#pragma unroll
    for (int i = 0; i < 4; i++) {
#pragma unroll
      for (int r = 0; r < 4; r++) {
        int grow = m0 + wm + i * 16 + quad * 4 + r;
        outz[(size_t)grow * N + gcol] = f2bf(acc[i][j][r] + bv);
      }
    }
  }
}

// ---------------- fused QKV GEMM BK=32 2-phase -----------------------------
__global__ __launch_bounds__(256, 4) void gemm_qkv(
    const u16* __restrict__ A, const u16* __restrict__ BT,
    const float* __restrict__ bq, const float* __restrict__ bk,
    const float* __restrict__ bvp,
    u16* __restrict__ qb, u16* __restrict__ kb, u16* __restrict__ vb) {
  const int K = 1024;
  __shared__ __align__(16) u16 As[2][128 * 32];
  __shared__ __align__(16) u16 Bs[2][128 * 32];
  int tid = threadIdx.x;
  int lane = tid & 63;
  int wave = tid >> 6;
  int quad = lane >> 4;
  int l16 = lane & 15;
  int mt, nt;
  swizzle_mn(mt, nt);
  int m0 = mt * 128;
  int n0 = nt * 128;
  int wm = (wave >> 1) * 64;
  int wn = (wave & 1) * 64;

  f32x4 zero = {0.f, 0.f, 0.f, 0.f};
  f32x4 acc[4][4];
#pragma unroll
  for (int i = 0; i < 4; i++)
#pragma unroll
    for (int j = 0; j < 4; j++) acc[i][j] = zero;

  int c0 = tid, c1 = tid + 256;
  const u16* ga0 = A + (size_t)(m0 + (c0 >> 2)) * K + (c0 & 3) * 8;
  const u16* ga1 = A + (size_t)(m0 + (c1 >> 2)) * K + (c1 & 3) * 8;
  const u16* gb0 = BT + (size_t)(n0 + (c0 >> 2)) * K + (c0 & 3) * 8;
  const u16* gb1 = BT + (size_t)(n0 + (c1 >> 2)) * K + (c1 & 3) * 8;

  GEMM_STAGE(0, 0);
  __syncthreads();
  for (int k0 = 0; k0 < K; k0 += 64) {
    if (k0 + 32 < K) GEMM_STAGE(1, k0 + 32);
    GEMM_COMPUTE(0);
    __syncthreads();
    if (k0 + 64 < K) GEMM_STAGE(0, k0 + 64);
    GEMM_COMPUTE(1);
    __syncthreads();
  }

  int region = n0 >> 10;
  const float* bias = region == 0 ? bq : (region == 1 ? bk : bvp);
  u16* outp = region == 0 ? qb : (region == 1 ? kb : vb);
  float scale = region == 0 ? 0.125f * 1.4426950408889634f : 1.f;

#pragma unroll
  for (int j = 0; j < 4; j++) {
    int gcol = (n0 & 1023) + wn + j * 16 + l16;
    float bv = bias[gcol];
    int h = gcol >> 6, hd = gcol & 63;
#pragma unroll
    for (int i = 0; i < 4; i++) {
#pragma unroll
      for (int r = 0; r < 4; r++) {
        int grow = m0 + wm + i * 16 + quad * 4 + r;
        float val = (acc[i][j][r] + bv) * scale;
        int b = grow >> 11, s = grow & 2047;
        if (region < 2) {
          outp[(((size_t)(b * H_ + h)) * S_ + s) * HD_ + hd] = f2bf(val);
        } else {
          outp[(((size_t)(b * H_ + h)) * HD_ + hd) * S_ + s] = f2bf(val);
        }
      }
    }
  }
}

// ---------------- flash attention: MQ=32/wave, double-buffered K/V ---------
// R13 structure + T5 s_setprio around MFMA clusters (m191: +4-7% on attn
// with phase-drifting blocks; 2 independent blocks/CU here).
__global__ __launch_bounds__(256, 2) void attn_kernel(
    const u16* __restrict__ q, const u16* __restrict__ k,
    const u16* __restrict__ vt, const int* __restrict__ mask,
    u16* __restrict__ ao, int qbase) {
  __shared__ __align__(16) u16 Ks[2][64 * 72];
  __shared__ __align__(16) u16 Vs[2][64 * 72];
  __shared__ __align__(16) u16 Ps[4][32 * 72];
  int tid = threadIdx.x;
  int lane = tid & 63;
  int wave = tid >> 6;
  int quad = lane >> 4;
  int l16 = lane & 15;
  int bh = blockIdx.y;
  int b = bh >> 4;
  int h = bh & 15;
  int qrow0 = (qbase + blockIdx.x) * 128 + wave * 32;

  const u16* qh = q + (size_t)bh * S_ * HD_;
  const u16* kh = k + (size_t)bh * S_ * HD_;
  const u16* vh = vt + (size_t)bh * HD_ * S_;

  bf16x8 qfA0 = *(const bf16x8*)(qh + (size_t)(qrow0 + l16) * HD_ + quad * 8);
  bf16x8 qfA1 = *(const bf16x8*)(qh + (size_t)(qrow0 + l16) * HD_ + 32 + quad * 8);
  bf16x8 qfB0 = *(const bf16x8*)(qh + (size_t)(qrow0 + 16 + l16) * HD_ + quad * 8);
  bf16x8 qfB1 = *(const bf16x8*)(qh + (size_t)(qrow0 + 16 + l16) * HD_ + 32 + quad * 8);

  int sr = tid >> 3, sc = tid & 7;
  const u16* kg0 = kh + sr * HD_ + sc * 8;
  const u16* kg1 = kh + (sr + 32) * HD_ + sc * 8;
  const u16* vg0 = vh + (size_t)sr * S_ + sc * 8;
  const u16* vg1 = vh + (size_t)(sr + 32) * S_ + sc * 8;
  int kr0 = (sr & 1) * 16 + (sr >> 1);
  int ko0 = kr0 * 72 + sc * 8;
  int ko1 = (32 + kr0) * 72 + sc * 8;
  int vo0 = sr * 72 + sc * 8;
  int vo1 = (sr + 32) * 72 + sc * 8;
  const int* mrow = mask + b * S_ + 2 * l16;

  float l_pA[4] = {0.f, 0.f, 0.f, 0.f};
  float l_pB[4] = {0.f, 0.f, 0.f, 0.f};
  f32x4 zero = {0.f, 0.f, 0.f, 0.f};
  f32x4 o_accA[4], o_accB[4];
#pragma unroll
  for (int c = 0; c < 4; c++) { o_accA[c] = zero; o_accB[c] = zero; }

  u16* pw = &Ps[wave][0];

  bf16x8 kv0 = *(const bf16x8*)(kg0);
  bf16x8 kv1 = *(const bf16x8*)(kg1);
  bf16x8 vv0 = *(const bf16x8*)(vg0);
  bf16x8 vv1 = *(const bf16x8*)(vg1);
  *(bf16x8*)&Ks[0][ko0] = kv0;
  *(bf16x8*)&Ks[0][ko1] = kv1;
  *(bf16x8*)&Vs[0][vo0] = vv0;
  *(bf16x8*)&Vs[0][vo1] = vv1;
  kv0 = *(const bf16x8*)(kg0 + (size_t)64 * HD_);
  kv1 = *(const bf16x8*)(kg1 + (size_t)64 * HD_);
  vv0 = *(const bf16x8*)(vg0 + 64);
  vv1 = *(const bf16x8*)(vg1 + 64);

  int cur = 0;
  for (int kt = 0; kt < S_; kt += 64) {
    int2 mk0 = *(const int2*)(mrow + kt);
    int2 mk1 = *(const int2*)(mrow + kt + 32);

    __syncthreads();
    if (kt + 64 < S_) {
      int alt = cur ^ 1;
      *(bf16x8*)&Ks[alt][ko0] = kv0;
      *(bf16x8*)&Ks[alt][ko1] = kv1;
      *(bf16x8*)&Vs[alt][vo0] = vv0;
      *(bf16x8*)&Vs[alt][vo1] = vv1;
      int nk = (kt + 128) & (S_ - 1);
      kv0 = *(const bf16x8*)(kg0 + (size_t)nk * HD_);
      kv1 = *(const bf16x8*)(kg1 + (size_t)nk * HD_);
      vv0 = *(const bf16x8*)(vg0 + nk);
      vv1 = *(const bf16x8*)(vg1 + nk);
    }

    const u16* ksb = &Ks[cur][0];
    const u16* vsb = &Vs[cur][0];
#pragma unroll
    for (int g = 0; g < 2; g++) {
      int2 mk = g == 0 ? mk0 : mk1;
      int rowe = (g * 32 + l16) * 72;
      int rowo = (g * 32 + 16 + l16) * 72;
      bf16x8 e0 = *(const bf16x8*)&ksb[rowe + quad * 8];
      bf16x8 e1 = *(const bf16x8*)&ksb[rowe + 32 + quad * 8];
      bf16x8 o0 = *(const bf16x8*)&ksb[rowo + quad * 8];
      bf16x8 o1 = *(const bf16x8*)&ksb[rowo + 32 + quad * 8];
      __builtin_amdgcn_s_setprio(1);
      f32x4 seA = mfma16(qfA1, e1, mfma16(qfA0, e0, zero));
      f32x4 soA = mfma16(qfA1, o1, mfma16(qfA0, o0, zero));
      f32x4 seB = mfma16(qfB1, e1, mfma16(qfB0, e0, zero));
      f32x4 soB = mfma16(qfB1, o1, mfma16(qfB0, o0, zero));
      __builtin_amdgcn_s_setprio(0);
#pragma unroll
      for (int r = 0; r < 4; r++) {
        float pA0 = mk.x ? exp2f(seA[r]) : 0.f;
        float pA1 = mk.y ? exp2f(soA[r]) : 0.f;
        float pB0 = mk.x ? exp2f(seB[r]) : 0.f;
        float pB1 = mk.y ? exp2f(soB[r]) : 0.f;
        l_pA[r] += pA0 + pA1;
        l_pB[r] += pB0 + pB1;
        unsigned pkA = __builtin_amdgcn_perm(__float_as_uint(pA1),
                                             __float_as_uint(pA0), 0x07060302u);
        unsigned pkB = __builtin_amdgcn_perm(__float_as_uint(pB1),
                                             __float_as_uint(pB0), 0x07060302u);
        *(unsigned*)&pw[(quad * 4 + r) * 72 + g * 32 + 2 * l16] = pkA;
        *(unsigned*)&pw[(16 + quad * 4 + r) * 72 + g * 32 + 2 * l16] = pkB;
      }
    }
    bf16x8 pfA0 = *(const bf16x8*)&pw[l16 * 72 + quad * 8];
    bf16x8 pfA1 = *(const bf16x8*)&pw[l16 * 72 + 32 + quad * 8];
    bf16x8 pfB0 = *(const bf16x8*)&pw[(16 + l16) * 72 + quad * 8];
    bf16x8 pfB1 = *(const bf16x8*)&pw[(16 + l16) * 72 + 32 + quad * 8];
    __builtin_amdgcn_s_setprio(1);
#pragma unroll
    for (int c = 0; c < 4; c++) {
      bf16x8 vf0 = *(const bf16x8*)&vsb[(c * 16 + l16) * 72 + quad * 8];
      bf16x8 vf1 = *(const bf16x8*)&vsb[(c * 16 + l16) * 72 + 32 + quad * 8];
      o_accA[c] = mfma16(pfA1, vf1, mfma16(pfA0, vf0, o_accA[c]));
      o_accB[c] = mfma16(pfB1, vf1, mfma16(pfB0, vf0, o_accB[c]));
    }
    __builtin_amdgcn_s_setprio(0);
    cur ^= 1;
  }

#pragma unroll
  for (int r = 0; r < 4; r++) {
    float sA = l_pA[r], sB = l_pB[r];
#pragma unroll
    for (int off = 1; off < 16; off <<= 1) {
      sA += __shfl_xor(sA, off);
      sB += __shfl_xor(sB, off);
    }
    float invA = 1.f / sA, invB = 1.f / sB;
    int srowA = qrow0 + quad * 4 + r;
    int srowB = qrow0 + 16 + quad * 4 + r;
#pragma unroll
    for (int c = 0; c < 4; c++) {
      ao[((size_t)(b * S_ + srowA)) * D_ + h * HD_ + c * 16 + l16] =
          f2bf(o_accA[c][r] * invA);
      ao[((size_t)(b * S_ + srowB)) * D_ + h * HD_ + c * 16 + l16] =
          f2bf(o_accB[c][r] * invB);
    }
  }
}

// ---------------- residual (f32 base + 2 bf16 partials) + layernorm --------
__global__ __launch_bounds__(256) void ln_kernel(
    const float* __restrict__ xa, const u16* __restrict__ add0,
    const u16* __restrict__ add1,
    const float* __restrict__ g, const float* __restrict__ be,
    u16* __restrict__ outb) {
  int row = blockIdx.x;
  int tid = threadIdx.x;
  int lane = tid & 63;
  int wv = tid >> 6;
  size_t off0 = (size_t)row * D_ + tid * 4;
  const float4 a = *(const float4*)(xa + off0);
  const ushort4 c = *(const ushort4*)(add0 + off0);
  const ushort4 d = *(const ushort4*)(add1 + off0);
  float v0 = a.x + bf2f(c.x) + bf2f(d.x);
  float v1 = a.y + bf2f(c.y) + bf2f(d.y);
  float v2 = a.z + bf2f(c.z) + bf2f(d.z);
  float v3 = a.w + bf2f(c.w) + bf2f(d.w);
  float s = v0 + v1 + v2 + v3;
  float sq = v0 * v0 + v1 * v1 + v2 * v2 + v3 * v3;
#pragma unroll
  for (int off = 1; off < 64; off <<= 1) {
    s += __shfl_xor(s, off);
    sq += __shfl_xor(sq, off);
  }
  __shared__ float red[8];
  if (lane == 0) { red[wv] = s; red[4 + wv] = sq; }
  __syncthreads();
  s = red[0] + red[1] + red[2] + red[3];
  sq = red[4] + red[5] + red[6] + red[7];
  float mean = s * (1.f / D_);
  float var = sq * (1.f / D_) - mean * mean;
  float rstd = rsqrtf(var + 1e-5f);
  const float4 gv = *(const float4*)(g + tid * 4);
  const float4 bv = *(const float4*)(be + tid * 4);
  float y0 = (v0 - mean) * rstd * gv.x + bv.x;
  float y1 = (v1 - mean) * rstd * gv.y + bv.y;
  float y2 = (v2 - mean) * rstd * gv.z + bv.z;
  float y3 = (v3 - mean) * rstd * gv.w + bv.w;
  ushort4 ob = {f2bf(y0), f2bf(y1), f2bf(y2), f2bf(y3)};
  *(ushort4*)(outb + off0) = ob;
}

// ---------------- residual (bf16 base + 4 bf16 partials) + layernorm -------
__global__ __launch_bounds__(256) void ln4_kernel(
    const u16* __restrict__ xa,
    const u16* __restrict__ a0, const u16* __restrict__ a1,
    const u16* __restrict__ a2, const u16* __restrict__ a3,
    const float* __restrict__ g, const float* __restrict__ be,
    float* __restrict__ outf) {
  int row = blockIdx.x;
  int tid = threadIdx.x;
  int lane = tid & 63;
  int wv = tid >> 6;
  size_t off0 = (size_t)row * D_ + tid * 4;
  const ushort4 a = *(const ushort4*)(xa + off0);
  const ushort4 c0 = *(const ushort4*)(a0 + off0);
  const ushort4 c1 = *(const ushort4*)(a1 + off0);
  const ushort4 c2 = *(const ushort4*)(a2 + off0);
  const ushort4 c3 = *(const ushort4*)(a3 + off0);
  float v0 = bf2f(a.x) + (bf2f(c0.x) + bf2f(c1.x)) + (bf2f(c2.x) + bf2f(c3.x));
  float v1 = bf2f(a.y) + (bf2f(c0.y) + bf2f(c1.y)) + (bf2f(c2.y) + bf2f(c3.y));
  float v2 = bf2f(a.z) + (bf2f(c0.z) + bf2f(c1.z)) + (bf2f(c2.z) + bf2f(c3.z));
  float v3 = bf2f(a.w) + (bf2f(c0.w) + bf2f(c1.w)) + (bf2f(c2.w) + bf2f(c3.w));
  float s = v0 + v1 + v2 + v3;
  float sq = v0 * v0 + v1 * v1 + v2 * v2 + v3 * v3;
#pragma unroll
  for (int off = 1; off < 64; off <<= 1) {
    s += __shfl_xor(s, off);
    sq += __shfl_xor(sq, off);
  }
  __shared__ float red[8];
  if (lane == 0) { red[wv] = s; red[4 + wv] = sq; }
  __syncthreads();
  s = red[0] + red[1] + red[2] + red[3];
  sq = red[4] + red[5] + red[6] + red[7];
  float mean = s * (1.f / D_);
  float var = sq * (1.f / D_) - mean * mean;
  float rstd = rsqrtf(var + 1e-5f);
  const float4 gv = *(const float4*)(g + tid * 4);
  const float4 bv = *(const float4*)(be + tid * 4);
  float y0 = (v0 - mean) * rstd * gv.x + bv.x;
  float y1 = (v1 - mean) * rstd * gv.y + bv.y;
  float y2 = (v2 - mean) * rstd * gv.z + bv.z;
  float y3 = (v3 - mean) * rstd * gv.w + bv.w;
  float4 o = {y0, y1, y2, y3};
  *(float4*)(outf + off0) = o;
}

extern "C" void kernel_launch(void* const* d_in, const int* in_sizes, int n_in,
                              void* d_out, int out_size, void* d_ws, size_t ws_size,
                              hipStream_t stream) {
  const float* x = (const float*)d_in[0];
  const int* mask = (const int*)d_in[1];
  const float* Wq = (const float*)d_in[2];
  const float* bq = (const float*)d_in[3];
  const float* Wk = (const float*)d_in[4];
  const float* bk = (const float*)d_in[5];
  const float* Wv = (const float*)d_in[6];
  const float* bv = (const float*)d_in[7];
  const float* Wo = (const float*)d_in[8];
  const float* bo = (const float*)d_in[9];
  const float* W1 = (const float*)d_in[10];
  const float* b1 = (const float*)d_in[11];
  const float* W2 = (const float*)d_in[12];
  const float* b2 = (const float*)d_in[13];
  const float* g1 = (const float*)d_in[14];
  const float* be1 = (const float*)d_in[15];
  const float* g2 = (const float*)d_in[16];
  const float* be2 = (const float*)d_in[17];

  const size_t MB = 1ull << 20;
  char* ws = (char*)d_ws;
  u16* wTq = (u16*)(ws + 0 * MB);   // [wTq;wTk;wTv] contiguous = fused QKV BT
  u16* wTk = (u16*)(ws + 2 * MB);
  u16* wTv = (u16*)(ws + 4 * MB);
  u16* wTo = (u16*)(ws + 6 * MB);
  u16* w1T = (u16*)(ws + 8 * MB);   // FF x D
  u16* w2T = (u16*)(ws + 16 * MB);  // D x FF (live through ffn2)
  u16* xb  = (u16*)(ws + 24 * MB);  // bf16 x (qkv A operand)
  u16* qb  = (u16*)(ws + 32 * MB);
  u16* kb  = (u16*)(ws + 40 * MB);
  u16* vb  = (u16*)(ws + 48 * MB);
  u16* ao  = (u16*)(ws + 56 * MB);
  u16* p0  = (u16*)(ws + 64 * MB);   // proj partials (bf16, 8MB each)
  u16* p1  = (u16*)(ws + 80 * MB);
  u16* x1b = (u16*)(ws + 40 * MB);   // reuse kb (dead after attn); live to ln4
  u16* h1  = (u16*)(ws + 48 * MB);   // 48..80 (vb/ao dead after ffn1 input)
  u16* f0  = (u16*)(ws + 80 * MB);   // ffn2 partials bf16 (p1 dead after LN1)
  u16* f1  = (u16*)(ws + 96 * MB);
  u16* f2  = (u16*)(ws + 112 * MB);
  u16* f3  = (u16*)(ws + 0 * MB);    // weights 0..16 dead by ffn2 time

  // fused prep (x cvt + all 6 weight transposes, 64x64 tiles) — 1 launch
  prep_kernel<<<dim3(7168), dim3(256), 0, stream>>>(
      x, xb, W1, w1T, W2, w2T, Wq, Wk, Wv, Wo, wTq, wTk, wTv, wTo);

  gemm_qkv<<<dim3(32, 24), dim3(256), 0, stream>>>(xb, wTq, bq, bk, bv, qb, kb, vb);

  // attn: MQ=32/wave, 512 blocks (2/CU), T5 setprio
  attn_kernel<<<dim3(16, B_ * H_), dim3(256), 0, stream>>>(qb, kb, vb, mask, ao, 0);

  // proj: split-K x2 (512 blocks), bf16 partials p0,p1
  gemm_bt_sk4<<<dim3(32, 8, 2), dim3(256), 0, stream>>>(
      ao, wTo, bo, p0, p1, p0, p0, 4096, 1024, 1024, 512);

  // LN1: f32 base x + bf16 partials -> bf16 x1b
  ln_kernel<<<dim3(4096), dim3(256), 0, stream>>>(
      x, p0, p1, g1, be1, x1b);

  // ffn1: 256^2 counted-vmcnt template, 256 blocks (1/CU)
  gemm256_relu<<<dim3(16, 16), dim3(512), 0, stream>>>(
      x1b, w1T, b1, h1, 4096, 4096, 1024);

  // ffn2: 128^2 2-phase split-K x4 (1024 blocks, 4/CU), bf16 partials f0..f3
  gemm_bt_sk4<<<dim3(32, 8, 4), dim3(256), 0, stream>>>(
      h1, w2T, b2, f0, f1, f2, f3, 4096, 1024, 4096, 1024);

  ln4_kernel<<<dim3(4096), dim3(256), 0, stream>>>(
      x1b, f0, f1, f2, f3, g2, be2, (float*)d_out);
}

// Round 19
// 350.650 us; speedup vs baseline: 1.0368x; 1.0183x over previous
//
#include <hip/hip_runtime.h>
#include <stdint.h>
#include <stddef.h>

#define B_ 2
#define S_ 2048
#define D_ 1024
#define H_ 16
#define HD_ 64
#define FF_ 4096

typedef unsigned short u16;
typedef __attribute__((ext_vector_type(8))) short bf16x8;
typedef __attribute__((ext_vector_type(4))) float f32x4;

__device__ __forceinline__ u16 f2bf(float f) {
  unsigned u = __float_as_uint(f);
  u += 0x7fffu + ((u >> 16) & 1u);
  return (u16)(u >> 16);
}

__device__ __forceinline__ float bf2f(u16 u) {
  return __uint_as_float(((unsigned)u) << 16);
}

__device__ __forceinline__ f32x4 mfma16(bf16x8 a, bf16x8 b, f32x4 c) {
  return __builtin_amdgcn_mfma_f32_16x16x32_bf16(a, b, c, 0, 0, 0);
}

__device__ __forceinline__ void gload16(const void* g, void* l) {
  __builtin_amdgcn_global_load_lds(
      (const __attribute__((address_space(1))) void*)g,
      (__attribute__((address_space(3))) void*)l, 16, 0, 0);
}

// XCD-aware block swizzle (bijective when gridDim.x % 8 == 0).
__device__ __forceinline__ void swizzle_mn(int& mt, int& nt) {
  int gm = gridDim.x;
  if ((gm & 7) == 0) {
    int bid = blockIdx.y * gm + blockIdx.x;
    int mper = gm >> 3;
    int xcd = bid & 7, idx = bid >> 3;
    mt = xcd * mper + (idx % mper);
    nt = idx / mper;
  } else {
    mt = blockIdx.x;
    nt = blockIdx.y;
  }
}

// ---------------- fused prep: x cvt + all weight transposes ----------------
// 64x64 transpose tiles (128B write segments). grid 7168.
__global__ __launch_bounds__(256) void prep_kernel(
    const float* __restrict__ x, u16* __restrict__ xb,
    const float* __restrict__ W1, u16* __restrict__ w1T,
    const float* __restrict__ W2, u16* __restrict__ w2T,
    const float* __restrict__ Wq, const float* __restrict__ Wk,
    const float* __restrict__ Wv, const float* __restrict__ Wo,
    u16* __restrict__ wTq, u16* __restrict__ wTk,
    u16* __restrict__ wTv, u16* __restrict__ wTo) {
  int bid = blockIdx.x;
  int tid = threadIdx.x;
  if (bid >= 3072) {  // cvt path (no barrier)
    int i = (bid - 3072) * 1024 + tid * 4;
    float4 v = *(const float4*)(x + i);
    ushort4 o = { f2bf(v.x), f2bf(v.y), f2bf(v.z), f2bf(v.w) };
    *(ushort4*)(xb + i) = o;
    return;
  }
  const float* W;
  u16* WT;
  int K, N, k0, n0;
  if (bid < 1024) {        // W1: K=1024 N=4096
    W = W1; WT = w1T; K = 1024; N = 4096;
    k0 = (bid & 15) * 64; n0 = (bid >> 4) * 64;
  } else if (bid < 2048) { // W2: K=4096 N=1024
    int t2 = bid - 1024;
    W = W2; WT = w2T; K = 4096; N = 1024;
    k0 = (t2 >> 4) * 64; n0 = (t2 & 15) * 64;
  } else {                 // 4 x DxD
    int t2 = bid - 2048;
    int z = t2 >> 8, r2 = t2 & 255;
    W = z == 0 ? Wq : (z == 1 ? Wk : (z == 2 ? Wv : Wo));
    WT = z == 0 ? wTq : (z == 1 ? wTk : (z == 2 ? wTv : wTo));
    K = 1024; N = 1024;
    k0 = (r2 & 15) * 64; n0 = (r2 >> 4) * 64;
  }
  __shared__ u16 t[64][68];
  int rr = tid >> 4;          // 0..15
  int cc = (tid & 15) * 4;    // 0..60
#pragma unroll
  for (int p = 0; p < 4; p++) {
    int row = rr + p * 16;
    float4 v = *(const float4*)(W + (size_t)(k0 + row) * N + n0 + cc);
    t[row][cc + 0] = f2bf(v.x); t[row][cc + 1] = f2bf(v.y);
    t[row][cc + 2] = f2bf(v.z); t[row][cc + 3] = f2bf(v.w);
  }
  __syncthreads();
  int s = tid & 15;
#pragma unroll
  for (int p = 0; p < 4; p++) {
    int r = rr + p * 16;      // n-row within tile
    ushort4 o = { t[s * 4 + 0][r], t[s * 4 + 1][r],
                  t[s * 4 + 2][r], t[s * 4 + 3][r] };
    *(ushort4*)(WT + (size_t)(n0 + r) * K + k0 + s * 4) = o;
  }
}

// ======== 128^2 2-phase GEMM macros ========================================
#define GEMM_STAGE(BUF, KK)                      \
  do {                                           \
    gload16(ga0 + (KK), &As[BUF][c0 * 8]);       \
    gload16(ga1 + (KK), &As[BUF][c1 * 8]);       \
    gload16(gb0 + (KK), &Bs[BUF][c0 * 8]);       \
    gload16(gb1 + (KK), &Bs[BUF][c1 * 8]);       \
  } while (0)

#define GEMM_COMPUTE(BUF)                                                   \
  do {                                                                      \
    bf16x8 af[4], bfr[4];                                                   \
    _Pragma("unroll") for (int i = 0; i < 4; i++)                           \
        af[i] = *(const bf16x8*)&As[BUF][(wm + i * 16 + l16) * 32 + quad * 8]; \
    _Pragma("unroll") for (int j = 0; j < 4; j++)                           \
        bfr[j] = *(const bf16x8*)&Bs[BUF][(wn + j * 16 + l16) * 32 + quad * 8]; \
    _Pragma("unroll") for (int i = 0; i < 4; i++)                           \
        _Pragma("unroll") for (int j = 0; j < 4; j++)                       \
            acc[i][j] = mfma16(af[i], bfr[j], acc[i][j]);                   \
  } while (0)

// ======== 256^2 counted-vmcnt template (ffn1) ==============================
#define G2_STAGE(BUF, KK)                        \
  do {                                           \
    gload16(gA0 + (KK), &As[BUF][c0 * 8]);       \
    gload16(gA1 + (KK), &As[BUF][c1 * 8]);       \
    gload16(gB0 + (KK), &Bs[BUF][c0 * 8]);       \
    gload16(gB1 + (KK), &Bs[BUF][c1 * 8]);       \
  } while (0)

#define G2_COMPUTE(BUF)                                                        \
  do {                                                                         \
    bf16x8 bfr[4];                                                             \
    _Pragma("unroll") for (int j = 0; j < 4; j++)                              \
        bfr[j] = *(const bf16x8*)&Bs[BUF][(wn + j * 16 + l16) * 32 + quad * 8]; \
    _Pragma("unroll") for (int i = 0; i < 8; i++) {                            \
      bf16x8 af = *(const bf16x8*)&As[BUF][(wm + i * 16 + l16) * 32 + quad * 8]; \
      _Pragma("unroll") for (int j = 0; j < 4; j++)                            \
          acc[i][j] = mfma16(af, bfr[j], acc[i][j]);                           \
    }                                                                          \
  } while (0)

#define G2_STEP(BUF, NXT, KNEXT)                        \
  do {                                                  \
    G2_STAGE(NXT, KNEXT);                               \
    asm volatile("s_waitcnt vmcnt(4)" ::: "memory");    \
    __builtin_amdgcn_s_barrier();                       \
    asm volatile("" ::: "memory");                      \
    G2_COMPUTE(BUF);                                    \
    asm volatile("" ::: "memory");                      \
    __builtin_amdgcn_s_barrier();                       \
  } while (0)

// ---------------- GEMM 256x256 counted-vmcnt, out bf16+relu [ffn1] ---------
__global__ __launch_bounds__(512, 2) void gemm256_relu(
    const u16* __restrict__ A, const u16* __restrict__ BT,
    const float* __restrict__ bias, u16* __restrict__ outp,
    int M, int N, int K) {
  __shared__ __align__(16) u16 As[2][256 * 32];
  __shared__ __align__(16) u16 Bs[2][256 * 32];
  int tid = threadIdx.x;
  int lane = tid & 63;
  int wave = tid >> 6;            // 0..7
  int quad = lane >> 4;
  int l16 = lane & 15;
  int mt, nt;
  swizzle_mn(mt, nt);
  int m0 = mt * 256;
  int n0 = nt * 256;
  int wm = (wave >> 2) * 128;     // 2 M-groups
  int wn = (wave & 3) * 64;       // 4 N-groups

  f32x4 zero = {0.f, 0.f, 0.f, 0.f};
  f32x4 acc[8][4];
#pragma unroll
  for (int i = 0; i < 8; i++)
#pragma unroll
    for (int j = 0; j < 4; j++) acc[i][j] = zero;

  int c0 = tid, c1 = tid + 512;   // chunk: row = c>>2, kcol = (c&3)*8
  const u16* gA0 = A + (size_t)(m0 + (c0 >> 2)) * K + (c0 & 3) * 8;
  const u16* gA1 = A + (size_t)(m0 + (c1 >> 2)) * K + (c1 & 3) * 8;
  const u16* gB0 = BT + (size_t)(n0 + (c0 >> 2)) * K + (c0 & 3) * 8;
  const u16* gB1 = BT + (size_t)(n0 + (c1 >> 2)) * K + (c1 & 3) * 8;

  G2_STAGE(0, 0);
  for (int k0 = 0; k0 < K; k0 += 64) {
    G2_STEP(0, 1, (k0 + 32 < K) ? k0 + 32 : 0);
    G2_STEP(1, 0, (k0 + 64 < K) ? k0 + 64 : 0);
  }

#pragma unroll
  for (int j = 0; j < 4; j++) {
    int gcol = n0 + wn + j * 16 + l16;
    float bv = bias[gcol];
#pragma unroll
    for (int i = 0; i < 8; i++) {
#pragma unroll
      for (int r = 0; r < 4; r++) {
        int grow = m0 + wm + i * 16 + quad * 4 + r;
        float val = acc[i][j][r] + bv;
        outp[(size_t)grow * N + gcol] = f2bf(val > 0.f ? val : 0.f);
      }
    }
  }
}

// ---------------- GEMM 128x128 BK=32 2-phase split-K, bf16 partials --------
__global__ __launch_bounds__(256, 4) void gemm_bt_sk4(
    const u16* __restrict__ A, const u16* __restrict__ BT,
    const float* __restrict__ bias,
    u16* __restrict__ o0, u16* __restrict__ o1,
    u16* __restrict__ o2, u16* __restrict__ o3,
    int M, int N, int K, int Kc) {
  __shared__ __align__(16) u16 As[2][128 * 32];
  __shared__ __align__(16) u16 Bs[2][128 * 32];
  int tid = threadIdx.x;
  int lane = tid & 63;
  int wave = tid >> 6;
  int quad = lane >> 4;
  int l16 = lane & 15;
  int mt, nt;
  swizzle_mn(mt, nt);
  int m0 = mt * 128;
  int n0 = nt * 128;
  int z = blockIdx.z;
  int kb = z * Kc;
  int wm = (wave >> 1) * 64;
  int wn = (wave & 1) * 64;

  f32x4 zero = {0.f, 0.f, 0.f, 0.f};
  f32x4 acc[4][4];
#pragma unroll
  for (int i = 0; i < 4; i++)
#pragma unroll
    for (int j = 0; j < 4; j++) acc[i][j] = zero;

  int c0 = tid, c1 = tid + 256;
  const u16* ga0 = A + (size_t)(m0 + (c0 >> 2)) * K + (c0 & 3) * 8 + kb;
  const u16* ga1 = A + (size_t)(m0 + (c1 >> 2)) * K + (c1 & 3) * 8 + kb;
  const u16* gb0 = BT + (size_t)(n0 + (c0 >> 2)) * K + (c0 & 3) * 8 + kb;
  const u16* gb1 = BT + (size_t)(n0 + (c1 >> 2)) * K + (c1 & 3) * 8 + kb;

  GEMM_STAGE(0, 0);
  __syncthreads();
  for (int k0 = 0; k0 < Kc; k0 += 64) {
    if (k0 + 32 < Kc) GEMM_STAGE(1, k0 + 32);
    GEMM_COMPUTE(0);
    __syncthreads();
    if (k0 + 64 < Kc) GEMM_STAGE(0, k0 + 64);
    GEMM_COMPUTE(1);
    __syncthreads();
  }

  u16* outz = z == 0 ? o0 : (z == 1 ? o1 : (z == 2 ? o2 : o3));
  float biasmul = (z == 0) ? 1.f : 0.f;
#pragma unroll
  for (int j = 0; j < 4; j++) {
    int gcol = n0 + wn + j * 16 + l16;
    float bv = bias[gcol] * biasmul;
#pragma unroll
    for (int i = 0; i < 4; i++) {
#pragma unroll
      for (int r = 0; r < 4; r++) {
        int grow = m0 + wm + i * 16 + quad * 4 + r;
        outz[(size_t)grow * N + gcol] = f2bf(acc[i][j][r] + bv);
      }
    }
  }
}

// ---------------- fused QKV GEMM BK=32 2-phase -----------------------------
__global__ __launch_bounds__(256, 4) void gemm_qkv(
    const u16* __restrict__ A, const u16* __restrict__ BT,
    const float* __restrict__ bq, const float* __restrict__ bk,
    const float* __restrict__ bvp,
    u16* __restrict__ qb, u16* __restrict__ kb, u16* __restrict__ vb) {
  const int K = 1024;
  __shared__ __align__(16) u16 As[2][128 * 32];
  __shared__ __align__(16) u16 Bs[2][128 * 32];
  int tid = threadIdx.x;
  int lane = tid & 63;
  int wave = tid >> 6;
  int quad = lane >> 4;
  int l16 = lane & 15;
  int mt, nt;
  swizzle_mn(mt, nt);
  int m0 = mt * 128;
  int n0 = nt * 128;
  int wm = (wave >> 1) * 64;
  int wn = (wave & 1) * 64;

  f32x4 zero = {0.f, 0.f, 0.f, 0.f};
  f32x4 acc[4][4];
#pragma unroll
  for (int i = 0; i < 4; i++)
#pragma unroll
    for (int j = 0; j < 4; j++) acc[i][j] = zero;

  int c0 = tid, c1 = tid + 256;
  const u16* ga0 = A + (size_t)(m0 + (c0 >> 2)) * K + (c0 & 3) * 8;
  const u16* ga1 = A + (size_t)(m0 + (c1 >> 2)) * K + (c1 & 3) * 8;
  const u16* gb0 = BT + (size_t)(n0 + (c0 >> 2)) * K + (c0 & 3) * 8;
  const u16* gb1 = BT + (size_t)(n0 + (c1 >> 2)) * K + (c1 & 3) * 8;

  GEMM_STAGE(0, 0);
  __syncthreads();
  for (int k0 = 0; k0 < K; k0 += 64) {
    if (k0 + 32 < K) GEMM_STAGE(1, k0 + 32);
    GEMM_COMPUTE(0);
    __syncthreads();
    if (k0 + 64 < K) GEMM_STAGE(0, k0 + 64);
    GEMM_COMPUTE(1);
    __syncthreads();
  }

  int region = n0 >> 10;
  const float* bias = region == 0 ? bq : (region == 1 ? bk : bvp);
  u16* outp = region == 0 ? qb : (region == 1 ? kb : vb);
  float scale = region == 0 ? 0.125f * 1.4426950408889634f : 1.f;

#pragma unroll
  for (int j = 0; j < 4; j++) {
    int gcol = (n0 & 1023) + wn + j * 16 + l16;
    float bv = bias[gcol];
    int h = gcol >> 6, hd = gcol & 63;
#pragma unroll
    for (int i = 0; i < 4; i++) {
#pragma unroll
      for (int r = 0; r < 4; r++) {
        int grow = m0 + wm + i * 16 + quad * 4 + r;
        float val = (acc[i][j][r] + bv) * scale;
        int b = grow >> 11, s = grow & 2047;
        if (region < 2) {
          outp[(((size_t)(b * H_ + h)) * S_ + s) * HD_ + hd] = f2bf(val);
        } else {
          outp[(((size_t)(b * H_ + h)) * HD_ + hd) * S_ + s] = f2bf(val);
        }
      }
    }
  }
}

// ---------------- flash attention: MQ=32/wave, double-buffered K/V ---------
// (measured plateau 72.5 us; linear decode, 2 blocks/CU = mapped optimum;
// T5 setprio tested R18: -3 us regression on this lockstep structure, removed)
__global__ __launch_bounds__(256, 2) void attn_kernel(
    const u16* __restrict__ q, const u16* __restrict__ k,
    const u16* __restrict__ vt, const int* __restrict__ mask,
    u16* __restrict__ ao, int qbase) {
  __shared__ __align__(16) u16 Ks[2][64 * 72];
  __shared__ __align__(16) u16 Vs[2][64 * 72];
  __shared__ __align__(16) u16 Ps[4][32 * 72];
  int tid = threadIdx.x;
  int lane = tid & 63;
  int wave = tid >> 6;
  int quad = lane >> 4;
  int l16 = lane & 15;
  int bh = blockIdx.y;
  int b = bh >> 4;
  int h = bh & 15;
  int qrow0 = (qbase + blockIdx.x) * 128 + wave * 32;

  const u16* qh = q + (size_t)bh * S_ * HD_;
  const u16* kh = k + (size_t)bh * S_ * HD_;
  const u16* vh = vt + (size_t)bh * HD_ * S_;

  bf16x8 qfA0 = *(const bf16x8*)(qh + (size_t)(qrow0 + l16) * HD_ + quad * 8);
  bf16x8 qfA1 = *(const bf16x8*)(qh + (size_t)(qrow0 + l16) * HD_ + 32 + quad * 8);
  bf16x8 qfB0 = *(const bf16x8*)(qh + (size_t)(qrow0 + 16 + l16) * HD_ + quad * 8);
  bf16x8 qfB1 = *(const bf16x8*)(qh + (size_t)(qrow0 + 16 + l16) * HD_ + 32 + quad * 8);

  int sr = tid >> 3, sc = tid & 7;
  const u16* kg0 = kh + sr * HD_ + sc * 8;
  const u16* kg1 = kh + (sr + 32) * HD_ + sc * 8;
  const u16* vg0 = vh + (size_t)sr * S_ + sc * 8;
  const u16* vg1 = vh + (size_t)(sr + 32) * S_ + sc * 8;
  int kr0 = (sr & 1) * 16 + (sr >> 1);
  int ko0 = kr0 * 72 + sc * 8;
  int ko1 = (32 + kr0) * 72 + sc * 8;
  int vo0 = sr * 72 + sc * 8;
  int vo1 = (sr + 32) * 72 + sc * 8;
  const int* mrow = mask + b * S_ + 2 * l16;

  float l_pA[4] = {0.f, 0.f, 0.f, 0.f};
  float l_pB[4] = {0.f, 0.f, 0.f, 0.f};
  f32x4 zero = {0.f, 0.f, 0.f, 0.f};
  f32x4 o_accA[4], o_accB[4];
#pragma unroll
  for (int c = 0; c < 4; c++) { o_accA[c] = zero; o_accB[c] = zero; }

  u16* pw = &Ps[wave][0];

  bf16x8 kv0 = *(const bf16x8*)(kg0);
  bf16x8 kv1 = *(const bf16x8*)(kg1);
  bf16x8 vv0 = *(const bf16x8*)(vg0);
  bf16x8 vv1 = *(const bf16x8*)(vg1);
  *(bf16x8*)&Ks[0][ko0] = kv0;
  *(bf16x8*)&Ks[0][ko1] = kv1;
  *(bf16x8*)&Vs[0][vo0] = vv0;
  *(bf16x8*)&Vs[0][vo1] = vv1;
  kv0 = *(const bf16x8*)(kg0 + (size_t)64 * HD_);
  kv1 = *(const bf16x8*)(kg1 + (size_t)64 * HD_);
  vv0 = *(const bf16x8*)(vg0 + 64);
  vv1 = *(const bf16x8*)(vg1 + 64);

  int cur = 0;
  for (int kt = 0; kt < S_; kt += 64) {
    int2 mk0 = *(const int2*)(mrow + kt);
    int2 mk1 = *(const int2*)(mrow + kt + 32);

    __syncthreads();
    if (kt + 64 < S_) {
      int alt = cur ^ 1;
      *(bf16x8*)&Ks[alt][ko0] = kv0;
      *(bf16x8*)&Ks[alt][ko1] = kv1;
      *(bf16x8*)&Vs[alt][vo0] = vv0;
      *(bf16x8*)&Vs[alt][vo1] = vv1;
      int nk = (kt + 128) & (S_ - 1);
      kv0 = *(const bf16x8*)(kg0 + (size_t)nk * HD_);
      kv1 = *(const bf16x8*)(kg1 + (size_t)nk * HD_);
      vv0 = *(const bf16x8*)(vg0 + nk);
      vv1 = *(const bf16x8*)(vg1 + nk);
    }

    const u16* ksb = &Ks[cur][0];
    const u16* vsb = &Vs[cur][0];
#pragma unroll
    for (int g = 0; g < 2; g++) {
      int2 mk = g == 0 ? mk0 : mk1;
      int rowe = (g * 32 + l16) * 72;
      int rowo = (g * 32 + 16 + l16) * 72;
      bf16x8 e0 = *(const bf16x8*)&ksb[rowe + quad * 8];
      bf16x8 e1 = *(const bf16x8*)&ksb[rowe + 32 + quad * 8];
      bf16x8 o0 = *(const bf16x8*)&ksb[rowo + quad * 8];
      bf16x8 o1 = *(const bf16x8*)&ksb[rowo + 32 + quad * 8];
      f32x4 seA = mfma16(qfA1, e1, mfma16(qfA0, e0, zero));
      f32x4 soA = mfma16(qfA1, o1, mfma16(qfA0, o0, zero));
      f32x4 seB = mfma16(qfB1, e1, mfma16(qfB0, e0, zero));
      f32x4 soB = mfma16(qfB1, o1, mfma16(qfB0, o0, zero));
#pragma unroll
      for (int r = 0; r < 4; r++) {
        float pA0 = mk.x ? exp2f(seA[r]) : 0.f;
        float pA1 = mk.y ? exp2f(soA[r]) : 0.f;
        float pB0 = mk.x ? exp2f(seB[r]) : 0.f;
        float pB1 = mk.y ? exp2f(soB[r]) : 0.f;
        l_pA[r] += pA0 + pA1;
        l_pB[r] += pB0 + pB1;
        unsigned pkA = __builtin_amdgcn_perm(__float_as_uint(pA1),
                                             __float_as_uint(pA0), 0x07060302u);
        unsigned pkB = __builtin_amdgcn_perm(__float_as_uint(pB1),
                                             __float_as_uint(pB0), 0x07060302u);
        *(unsigned*)&pw[(quad * 4 + r) * 72 + g * 32 + 2 * l16] = pkA;
        *(unsigned*)&pw[(16 + quad * 4 + r) * 72 + g * 32 + 2 * l16] = pkB;
      }
    }
    bf16x8 pfA0 = *(const bf16x8*)&pw[l16 * 72 + quad * 8];
    bf16x8 pfA1 = *(const bf16x8*)&pw[l16 * 72 + 32 + quad * 8];
    bf16x8 pfB0 = *(const bf16x8*)&pw[(16 + l16) * 72 + quad * 8];
    bf16x8 pfB1 = *(const bf16x8*)&pw[(16 + l16) * 72 + 32 + quad * 8];
#pragma unroll
    for (int c = 0; c < 4; c++) {
      bf16x8 vf0 = *(const bf16x8*)&vsb[(c * 16 + l16) * 72 + quad * 8];
      bf16x8 vf1 = *(const bf16x8*)&vsb[(c * 16 + l16) * 72 + 32 + quad * 8];
      o_accA[c] = mfma16(pfA1, vf1, mfma16(pfA0, vf0, o_accA[c]));
      o_accB[c] = mfma16(pfB1, vf1, mfma16(pfB0, vf0, o_accB[c]));
    }
    cur ^= 1;
  }

#pragma unroll
  for (int r = 0; r < 4; r++) {
    float sA = l_pA[r], sB = l_pB[r];
#pragma unroll
    for (int off = 1; off < 16; off <<= 1) {
      sA += __shfl_xor(sA, off);
      sB += __shfl_xor(sB, off);
    }
    float invA = 1.f / sA, invB = 1.f / sB;
    int srowA = qrow0 + quad * 4 + r;
    int srowB = qrow0 + 16 + quad * 4 + r;
#pragma unroll
    for (int c = 0; c < 4; c++) {
      ao[((size_t)(b * S_ + srowA)) * D_ + h * HD_ + c * 16 + l16] =
          f2bf(o_accA[c][r] * invA);
      ao[((size_t)(b * S_ + srowB)) * D_ + h * HD_ + c * 16 + l16] =
          f2bf(o_accB[c][r] * invB);
    }
  }
}

// ---------------- residual (f32 base + 2 bf16 partials) + layernorm --------
__global__ __launch_bounds__(256) void ln_kernel(
    const float* __restrict__ xa, const u16* __restrict__ add0,
    const u16* __restrict__ add1,
    const float* __restrict__ g, const float* __restrict__ be,
    u16* __restrict__ outb) {
  int row = blockIdx.x;
  int tid = threadIdx.x;
  int lane = tid & 63;
  int wv = tid >> 6;
  size_t off0 = (size_t)row * D_ + tid * 4;
  const float4 a = *(const float4*)(xa + off0);
  const ushort4 c = *(const ushort4*)(add0 + off0);
  const ushort4 d = *(const ushort4*)(add1 + off0);
  float v0 = a.x + bf2f(c.x) + bf2f(d.x);
  float v1 = a.y + bf2f(c.y) + bf2f(d.y);
  float v2 = a.z + bf2f(c.z) + bf2f(d.z);
  float v3 = a.w + bf2f(c.w) + bf2f(d.w);
  float s = v0 + v1 + v2 + v3;
  float sq = v0 * v0 + v1 * v1 + v2 * v2 + v3 * v3;
#pragma unroll
  for (int off = 1; off < 64; off <<= 1) {
    s += __shfl_xor(s, off);
    sq += __shfl_xor(sq, off);
  }
  __shared__ float red[8];
  if (lane == 0) { red[wv] = s; red[4 + wv] = sq; }
  __syncthreads();
  s = red[0] + red[1] + red[2] + red[3];
  sq = red[4] + red[5] + red[6] + red[7];
  float mean = s * (1.f / D_);
  float var = sq * (1.f / D_) - mean * mean;
  float rstd = rsqrtf(var + 1e-5f);
  const float4 gv = *(const float4*)(g + tid * 4);
  const float4 bv = *(const float4*)(be + tid * 4);
  float y0 = (v0 - mean) * rstd * gv.x + bv.x;
  float y1 = (v1 - mean) * rstd * gv.y + bv.y;
  float y2 = (v2 - mean) * rstd * gv.z + bv.z;
  float y3 = (v3 - mean) * rstd * gv.w + bv.w;
  ushort4 ob = {f2bf(y0), f2bf(y1), f2bf(y2), f2bf(y3)};
  *(ushort4*)(outb + off0) = ob;
}

// ---------------- residual (bf16 base + 4 bf16 partials) + layernorm -------
__global__ __launch_bounds__(256) void ln4_kernel(
    const u16* __restrict__ xa,
    const u16* __restrict__ a0, const u16* __restrict__ a1,
    const u16* __restrict__ a2, const u16* __restrict__ a3,
    const float* __restrict__ g, const float* __restrict__ be,
    float* __restrict__ outf) {
  int row = blockIdx.x;
  int tid = threadIdx.x;
  int lane = tid & 63;
  int wv = tid >> 6;
  size_t off0 = (size_t)row * D_ + tid * 4;
  const ushort4 a = *(const ushort4*)(xa + off0);
  const ushort4 c0 = *(const ushort4*)(a0 + off0);
  const ushort4 c1 = *(const ushort4*)(a1 + off0);
  const ushort4 c2 = *(const ushort4*)(a2 + off0);
  const ushort4 c3 = *(const ushort4*)(a3 + off0);
  float v0 = bf2f(a.x) + (bf2f(c0.x) + bf2f(c1.x)) + (bf2f(c2.x) + bf2f(c3.x));
  float v1 = bf2f(a.y) + (bf2f(c0.y) + bf2f(c1.y)) + (bf2f(c2.y) + bf2f(c3.y));
  float v2 = bf2f(a.z) + (bf2f(c0.z) + bf2f(c1.z)) + (bf2f(c2.z) + bf2f(c3.z));
  float v3 = bf2f(a.w) + (bf2f(c0.w) + bf2f(c1.w)) + (bf2f(c2.w) + bf2f(c3.w));
  float s = v0 + v1 + v2 + v3;
  float sq = v0 * v0 + v1 * v1 + v2 * v2 + v3 * v3;
#pragma unroll
  for (int off = 1; off < 64; off <<= 1) {
    s += __shfl_xor(s, off);
    sq += __shfl_xor(sq, off);
  }
  __shared__ float red[8];
  if (lane == 0) { red[wv] = s; red[4 + wv] = sq; }
  __syncthreads();
  s = red[0] + red[1] + red[2] + red[3];
  sq = red[4] + red[5] + red[6] + red[7];
  float mean = s * (1.f / D_);
  float var = sq * (1.f / D_) - mean * mean;
  float rstd = rsqrtf(var + 1e-5f);
  const float4 gv = *(const float4*)(g + tid * 4);
  const float4 bv = *(const float4*)(be + tid * 4);
  float y0 = (v0 - mean) * rstd * gv.x + bv.x;
  float y1 = (v1 - mean) * rstd * gv.y + bv.y;
  float y2 = (v2 - mean) * rstd * gv.z + bv.z;
  float y3 = (v3 - mean) * rstd * gv.w + bv.w;
  float4 o = {y0, y1, y2, y3};
  *(float4*)(outf + off0) = o;
}

extern "C" void kernel_launch(void* const* d_in, const int* in_sizes, int n_in,
                              void* d_out, int out_size, void* d_ws, size_t ws_size,
                              hipStream_t stream) {
  const float* x = (const float*)d_in[0];
  const int* mask = (const int*)d_in[1];
  const float* Wq = (const float*)d_in[2];
  const float* bq = (const float*)d_in[3];
  const float* Wk = (const float*)d_in[4];
  const float* bk = (const float*)d_in[5];
  const float* Wv = (const float*)d_in[6];
  const float* bv = (const float*)d_in[7];
  const float* Wo = (const float*)d_in[8];
  const float* bo = (const float*)d_in[9];
  const float* W1 = (const float*)d_in[10];
  const float* b1 = (const float*)d_in[11];
  const float* W2 = (const float*)d_in[12];
  const float* b2 = (const float*)d_in[13];
  const float* g1 = (const float*)d_in[14];
  const float* be1 = (const float*)d_in[15];
  const float* g2 = (const float*)d_in[16];
  const float* be2 = (const float*)d_in[17];

  const size_t MB = 1ull << 20;
  char* ws = (char*)d_ws;
  u16* wTq = (u16*)(ws + 0 * MB);   // [wTq;wTk;wTv] contiguous = fused QKV BT
  u16* wTk = (u16*)(ws + 2 * MB);
  u16* wTv = (u16*)(ws + 4 * MB);
  u16* wTo = (u16*)(ws + 6 * MB);
  u16* w1T = (u16*)(ws + 8 * MB);   // FF x D
  u16* w2T = (u16*)(ws + 16 * MB);  // D x FF (live through ffn2)
  u16* xb  = (u16*)(ws + 24 * MB);  // bf16 x (qkv A operand)
  u16* qb  = (u16*)(ws + 32 * MB);
  u16* kb  = (u16*)(ws + 40 * MB);
  u16* vb  = (u16*)(ws + 48 * MB);
  u16* ao  = (u16*)(ws + 56 * MB);
  u16* p0  = (u16*)(ws + 64 * MB);   // proj partials (bf16, 8MB each)
  u16* p1  = (u16*)(ws + 80 * MB);
  u16* x1b = (u16*)(ws + 40 * MB);   // reuse kb (dead after attn); live to ln4
  u16* h1  = (u16*)(ws + 48 * MB);   // 48..80 (vb/ao dead after ffn1 input)
  u16* f0  = (u16*)(ws + 80 * MB);   // ffn2 partials bf16 (p1 dead after LN1)
  u16* f1  = (u16*)(ws + 96 * MB);
  u16* f2  = (u16*)(ws + 112 * MB);
  u16* f3  = (u16*)(ws + 0 * MB);    // weights 0..16 dead by ffn2 time

  // fused prep (x cvt + all 6 weight transposes, 64x64 tiles) — 1 launch
  prep_kernel<<<dim3(7168), dim3(256), 0, stream>>>(
      x, xb, W1, w1T, W2, w2T, Wq, Wk, Wv, Wo, wTq, wTk, wTv, wTo);

  gemm_qkv<<<dim3(32, 24), dim3(256), 0, stream>>>(xb, wTq, bq, bk, bv, qb, kb, vb);

  // attn: MQ=32/wave, 512 blocks (2/CU)
  attn_kernel<<<dim3(16, B_ * H_), dim3(256), 0, stream>>>(qb, kb, vb, mask, ao, 0);

  // proj: split-K x2 (512 blocks), bf16 partials p0,p1
  gemm_bt_sk4<<<dim3(32, 8, 2), dim3(256), 0, stream>>>(
      ao, wTo, bo, p0, p1, p0, p0, 4096, 1024, 1024, 512);

  // LN1: f32 base x + bf16 partials -> bf16 x1b
  ln_kernel<<<dim3(4096), dim3(256), 0, stream>>>(
      x, p0, p1, g1, be1, x1b);

  // ffn1: 256^2 counted-vmcnt template, 256 blocks (1/CU)
  gemm256_relu<<<dim3(16, 16), dim3(512), 0, stream>>>(
      x1b, w1T, b1, h1, 4096, 4096, 1024);

  // ffn2: 128^2 2-phase split-K x4 (1024 blocks, 4/CU), bf16 partials f0..f3
  gemm_bt_sk4<<<dim3(32, 8, 4), dim3(256), 0, stream>>>(
      h1, w2T, b2, f0, f1, f2, f3, 4096, 1024, 4096, 1024);

  ln4_kernel<<<dim3(4096), dim3(256), 0, stream>>>(
      x1b, f0, f1, f2, f3, g2, be2, (float*)d_out);
}